// Round 14
// baseline (1932.534 us; speedup 1.0000x reference)
//
#include <hip/hip_runtime.h>

typedef unsigned short u16;
typedef unsigned long long u64;
typedef __attribute__((ext_vector_type(8))) short short8;
typedef __attribute__((ext_vector_type(4))) float f32x4;

__device__ __forceinline__ u16 f2b(float f) {
  union { float f; unsigned u; } x; x.f = f;
  unsigned r = x.u + 0x7fffu + ((x.u >> 16) & 1u);
  return (u16)(r >> 16);
}
__device__ __forceinline__ float b2f(u16 h) {
  union { unsigned u; float f; } x; x.u = ((unsigned)h) << 16;
  return x.f;
}
__device__ __forceinline__ void gld16(const void* g, void* l) {
  __builtin_amdgcn_global_load_lds(
      (__attribute__((address_space(1))) const void*)g,
      (__attribute__((address_space(3))) void*)l, 16, 0, 0);
}

// ---------------- embedding: t[b,n,:] = emb[idx]*data or fusion ----------------
__global__ __launch_bounds__(256) void embed_k(
    const float* __restrict__ data, const int* __restrict__ idx,
    const float* __restrict__ emb, const float* __restrict__ fus,
    float* __restrict__ t) {
  int row = blockIdx.x;            // 0..4159
  int b = row / 1040, n = row % 1040;
  int tid = threadIdx.x;
  const float4* src;
  float sc = 1.f;
  if (n < 1024) {
    int e = idx[b * 1024 + n];
    sc = data[b * 1024 + n];
    src = (const float4*)(emb + (long)e * 1024);
  } else {
    src = (const float4*)(fus + (long)(n - 1024) * 1024);
  }
  float4 v = src[tid];
  v.x *= sc; v.y *= sc; v.z *= sc; v.w *= sc;
  ((float4*)(t + (long)row * 1024))[tid] = v;
}

// ------------- fused 5-matrix weight transpose: f32 src[K][N] -> bf16 dst[Npad][Kpad]
//               f1T gets COLUMN-PERMUTED layout (swiglu pairs interleaved 16/16) -------------
__global__ __launch_bounds__(256) void wtrans5_k(
    const float* __restrict__ sWq, const float* __restrict__ sWkv,
    const float* __restrict__ sWo, const float* __restrict__ sW1,
    const float* __restrict__ sW2,
    u16* __restrict__ dQkvT, u16* __restrict__ dWoT,
    u16* __restrict__ dF1T, u16* __restrict__ dF2T) {
  int id = blockIdx.x;
  const float* src; u16* dst; int K, N, Kpad, nx; float sc = 1.f; int perm = 0;
  if (id < 1024)       { src = sWq;  dst = dQkvT;             K = 1024; N = 1024; Kpad = 1024; nx = 32; sc = 0.125f; }
  else if (id < 3072)  { id -= 1024; src = sWkv; dst = dQkvT + 1024 * 1024; K = 1024; N = 2048; Kpad = 1024; nx = 64; }
  else if (id < 4096)  { id -= 3072; src = sWo;  dst = dWoT;  K = 1024; N = 1024; Kpad = 1024; nx = 32; }
  else if (id < 9600)  { id -= 4096; src = sW1;  dst = dF1T;  K = 1024; N = 5504; Kpad = 1024; nx = 172; perm = 1; }
  else                 { id -= 9600; src = sW2;  dst = dF2T;  K = 2730; N = 1024; Kpad = 2752; nx = 32; }
  int n0 = (id % nx) * 32, k0 = (id / nx) * 32;
  __shared__ float tile[32][33];
  int x = threadIdx.x & 31, y = threadIdx.x >> 5;
#pragma unroll
  for (int i = 0; i < 4; i++) {
    int k = k0 + y + i * 8, n = n0 + x;
    float val = 0.f;
    if (perm) {
      int p = n >> 5, sub = n & 31;
      int o = (sub < 16) ? (p * 16 + sub) : (2714 + p * 16 + sub);
      bool ok = (sub < 16) ? (o < 2730) : (o < 5460);
      val = (k < K && ok) ? src[(long)k * 5460 + o] : 0.f;
    } else {
      val = (k < K && n < N) ? src[(long)k * N + n] * sc : 0.f;
    }
    tile[y + i * 8][x] = val;
  }
  __syncthreads();
#pragma unroll
  for (int i = 0; i < 4; i++) {
    int n = n0 + y + i * 8, k = k0 + x;
    dst[(long)n * Kpad + k] = f2b(tile[x][y + i * 8]);
  }
}

// ---------------- LayerNorm (biased var, eps 1e-5) -> bf16 ----------------
__global__ __launch_bounds__(256) void ln_k(
    const float* __restrict__ t, const float* __restrict__ g,
    u16* __restrict__ xn) {
  int row = blockIdx.x, tid = threadIdx.x;
  int wave = tid >> 6, lane = tid & 63;
  float4 v = ((const float4*)(t + (long)row * 1024))[tid];
  float s = v.x + v.y + v.z + v.w;
#pragma unroll
  for (int o = 32; o > 0; o >>= 1) s += __shfl_xor(s, o, 64);
  __shared__ float r1[4], r2[4];
  if (lane == 0) r1[wave] = s;
  __syncthreads();
  float mean = (r1[0] + r1[1] + r1[2] + r1[3]) * (1.f / 1024.f);
  float dx = v.x - mean, dy = v.y - mean, dz = v.z - mean, dw = v.w - mean;
  float q = dx * dx + dy * dy + dz * dz + dw * dw;
#pragma unroll
  for (int o = 32; o > 0; o >>= 1) q += __shfl_xor(q, o, 64);
  if (lane == 0) r2[wave] = q;
  __syncthreads();
  float var = (r2[0] + r2[1] + r2[2] + r2[3]) * (1.f / 1024.f);
  float inv = rsqrtf(var + 1e-5f);
  float4 gv = ((const float4*)g)[tid];
  u64 pack = (u64)f2b(dx * inv * gv.x)
           | ((u64)f2b(dy * inv * gv.y) << 16)
           | ((u64)f2b(dz * inv * gv.z) << 32)
           | ((u64)f2b(dw * inv * gv.w) << 48);
  *(u64*)(xn + (long)row * 1024 + tid * 4) = pack;
}

// ---------------- final-LN row stats ----------------
__global__ __launch_bounds__(256) void rowstats_k(
    const float* __restrict__ t, float* __restrict__ rowm, float* __restrict__ rinv) {
  int row = blockIdx.x, tid = threadIdx.x;
  int wave = tid >> 6, lane = tid & 63;
  float4 v = ((const float4*)(t + (long)row * 1024))[tid];
  float s = v.x + v.y + v.z + v.w;
#pragma unroll
  for (int o = 32; o > 0; o >>= 1) s += __shfl_xor(s, o, 64);
  __shared__ float r1[4], r2[4];
  if (lane == 0) r1[wave] = s;
  __syncthreads();
  float mean = (r1[0] + r1[1] + r1[2] + r1[3]) * (1.f / 1024.f);
  float dx = v.x - mean, dy = v.y - mean, dz = v.z - mean, dw = v.w - mean;
  float q = dx * dx + dy * dy + dz * dz + dw * dw;
#pragma unroll
  for (int o = 32; o > 0; o >>= 1) q += __shfl_xor(q, o, 64);
  if (lane == 0) r2[wave] = q;
  __syncthreads();
  if (tid == 0) {
    float var = (r2[0] + r2[1] + r2[2] + r2[3]) * (1.f / 1024.f);
    rowm[row] = mean;
    rinv[row] = rsqrtf(var + 1e-5f);
  }
}

// ------- GEMM: C[M][N] = A[M][K](bf16) * Bt[N][K](bf16)^T, tile 128x128, BK=32
// mode0: bf16 store; mode2: bf16 + fused V-transpose; mode3: fused SwiGLU epilogue
// T4 counted-vmcnt 3-deep pipeline; T2 XOR-swizzled LDS; bijective-XCD-swizzled 1D grid.
__global__ __launch_bounds__(256) void gemm_bt(
    const u16* __restrict__ A, int lda,
    const u16* __restrict__ Bt, int ldb,
    void* __restrict__ C, int ldc,
    int K, int mode, int gx, u16* __restrict__ vt) {
  __shared__ u16 As[3][128 * 32];
  __shared__ u16 Bs[3][128 * 32];
  int tid = threadIdx.x;
  int wave = tid >> 6, lane = tid & 63;
  int col = lane & 15, grp = lane >> 4;
  int nwg = gridDim.x;
  int id = blockIdx.x;
  int q = nwg >> 3, r = nwg & 7;
  int xcd = id & 7, off = id >> 3;
  int wgid = (xcd < r ? xcd * (q + 1) : r * (q + 1) + (xcd - r) * q) + off;
  int bm = wgid % gx, bn = wgid / gx;
  int sr = wave * 16 + (lane >> 2);
  int sk = ((lane & 3) ^ ((lane >> 3) & 3)) * 8;
  const u16* aSrc = A + ((long)bm * 128 + sr) * lda + sk;
  const u16* bSrc = Bt + ((long)bn * 128 + sr) * ldb + sk;
  int wm = (wave >> 1) * 64, wn = (wave & 1) * 64;
  f32x4 acc[4][4] = {};

#define GSTAGE(buf, kt) do { \
    _Pragma("unroll") \
    for (int qq = 0; qq < 2; qq++) { \
      gld16(aSrc + (kt) + (long)qq * 64 * lda, &As[buf][wave * 512 + qq * 2048]); \
      gld16(bSrc + (kt) + (long)qq * 64 * ldb, &Bs[buf][wave * 512 + qq * 2048]); \
    } } while (0)

  GSTAGE(0, 0);
  if (32 < K) GSTAGE(1, 32);
  int cur = 0;
  int slot = (grp ^ ((col >> 1) & 3)) * 8;
  for (int kt = 0; kt < K; kt += 32) {
    if (kt + 64 < K) {
      int nb = cur + 2; if (nb >= 3) nb -= 3;
      GSTAGE(nb, kt + 64);
      asm volatile("s_waitcnt vmcnt(8)" ::: "memory");
    } else if (kt + 32 < K) {
      asm volatile("s_waitcnt vmcnt(4)" ::: "memory");
    } else {
      asm volatile("s_waitcnt vmcnt(0)" ::: "memory");
    }
    __builtin_amdgcn_s_barrier();
    __builtin_amdgcn_sched_barrier(0);
    short8 af[4], bfv[4];
#pragma unroll
    for (int m = 0; m < 4; m++)
      af[m] = *(const short8*)&As[cur][(wm + m * 16 + col) * 32 + slot];
#pragma unroll
    for (int n = 0; n < 4; n++)
      bfv[n] = *(const short8*)&Bs[cur][(wn + n * 16 + col) * 32 + slot];
    __builtin_amdgcn_s_setprio(1);
#pragma unroll
    for (int m = 0; m < 4; m++)
#pragma unroll
      for (int n = 0; n < 4; n++)
        acc[m][n] = __builtin_amdgcn_mfma_f32_16x16x32_bf16(af[m], bfv[n], acc[m][n], 0, 0, 0);
    __builtin_amdgcn_s_setprio(0);
    __builtin_amdgcn_s_barrier();
    __builtin_amdgcn_sched_barrier(0);
    cur = (cur == 2) ? 0 : cur + 1;
  }
#undef GSTAGE
  long r0 = (long)bm * 128 + wm + grp * 4;
  int c0 = bn * 128 + wn + col;
  if (mode == 3) {
    // fused SwiGLU: fragment n even = xh block p, n odd = gate block p (same p)
    u16* Ab = (u16*)C;
#pragma unroll
    for (int m = 0; m < 4; m++)
#pragma unroll
      for (int np = 0; np < 2; np++) {
        int ac = ((bn * 4 + (wn >> 5) + np) << 4) + col;
#pragma unroll
        for (int rr = 0; rr < 4; rr++) {
          float xh = acc[m][np * 2][rr];
          float gt = acc[m][np * 2 + 1][rr];
          float rv = 0.f;
          if (ac < 2730)
            rv = 0.5f * gt * (1.f + erff(gt * 0.70710678118f)) * xh;
          Ab[(r0 + m * 16 + rr) * ldc + ac] = f2b(rv);
        }
      }
  } else {
    u16* Cb = (u16*)C;
#pragma unroll
    for (int m = 0; m < 4; m++)
#pragma unroll
      for (int n = 0; n < 4; n++)
#pragma unroll
        for (int rr = 0; rr < 4; rr++)
          Cb[(r0 + m * 16 + rr) * ldc + c0 + n * 16] = f2b(acc[m][n][rr]);
    if (mode == 2 && bn >= 16) {
      // fused V-transpose: vt[(b*16+h)*64 + d][j] = C[row=b*1040+j][2048 + h*64 + d]
#pragma unroll
      for (int m = 0; m < 4; m++) {
        long row = r0 + m * 16;
        if (row < 4160) {
          int bidx = (int)(row / 1040);
          int j = (int)(row - (long)bidx * 1040);
#pragma unroll
          for (int n = 0; n < 4; n++) {
            int d = c0 + n * 16 - 2048;
            u64 pack = (u64)f2b(acc[m][n][0])
                     | ((u64)f2b(acc[m][n][1]) << 16)
                     | ((u64)f2b(acc[m][n][2]) << 32)
                     | ((u64)f2b(acc[m][n][3]) << 48);
            *(u64*)(vt + ((long)(bidx * 16 + (d >> 6)) * 64 + (d & 63)) * 1040 + j) = pack;
          }
        }
      }
    }
  }
}

// ------- GEMM 64x128 tile, BK=32, residual RMW epilogue: T[M][1024] += A*Bt^T
// Each block exclusively owns a 64x128 patch of T -> plain non-atomic +=.
// Same T2 swizzle / T4 counted-vmcnt pipeline (3 vmem ops per stage). -------
__global__ __launch_bounds__(256) void gemm64_rmw(
    const u16* __restrict__ A, int lda,
    const u16* __restrict__ Bt, int ldb,
    float* __restrict__ T, int K, int gx) {
  __shared__ u16 As[3][64 * 32];
  __shared__ u16 Bs[3][128 * 32];
  int tid = threadIdx.x;
  int wave = tid >> 6, lane = tid & 63;
  int col = lane & 15, grp = lane >> 4;
  int nwg = gridDim.x;
  int id = blockIdx.x;
  int q = nwg >> 3, r = nwg & 7;
  int xcd = id & 7, off = id >> 3;
  int wgid = (xcd < r ? xcd * (q + 1) : r * (q + 1) + (xcd - r) * q) + off;
  int bm = wgid % gx, bn = wgid / gx;
  int sr = wave * 16 + (lane >> 2);              // rows 0..63 across 4 waves
  int sk = ((lane & 3) ^ ((lane >> 3) & 3)) * 8; // T2 pre-swizzled source chunk
  const u16* aSrc = A + ((long)bm * 64 + sr) * lda + sk;
  const u16* bSrc = Bt + ((long)bn * 128 + sr) * ldb + sk;
  int wm = (wave >> 1) * 32, wn = (wave & 1) * 64;
  f32x4 acc[2][4] = {};

#define GSTAGE64(buf, kt) do { \
    gld16(aSrc + (kt), &As[buf][wave * 512]); \
    _Pragma("unroll") \
    for (int qq = 0; qq < 2; qq++) \
      gld16(bSrc + (kt) + (long)qq * 64 * ldb, &Bs[buf][qq * 2048 + wave * 512]); \
    } while (0)

  GSTAGE64(0, 0);
  if (32 < K) GSTAGE64(1, 32);
  int cur = 0;
  int slot = (grp ^ ((col >> 1) & 3)) * 8;
  for (int kt = 0; kt < K; kt += 32) {
    if (kt + 64 < K) {
      int nb = cur + 2; if (nb >= 3) nb -= 3;
      GSTAGE64(nb, kt + 64);
      asm volatile("s_waitcnt vmcnt(6)" ::: "memory");   // stage t done; t+1,t+2 in flight
    } else if (kt + 32 < K) {
      asm volatile("s_waitcnt vmcnt(3)" ::: "memory");
    } else {
      asm volatile("s_waitcnt vmcnt(0)" ::: "memory");
    }
    __builtin_amdgcn_s_barrier();
    __builtin_amdgcn_sched_barrier(0);
    short8 af[2], bfv[4];
#pragma unroll
    for (int m = 0; m < 2; m++)
      af[m] = *(const short8*)&As[cur][(wm + m * 16 + col) * 32 + slot];
#pragma unroll
    for (int n = 0; n < 4; n++)
      bfv[n] = *(const short8*)&Bs[cur][(wn + n * 16 + col) * 32 + slot];
    __builtin_amdgcn_s_setprio(1);
#pragma unroll
    for (int m = 0; m < 2; m++)
#pragma unroll
      for (int n = 0; n < 4; n++)
        acc[m][n] = __builtin_amdgcn_mfma_f32_16x16x32_bf16(af[m], bfv[n], acc[m][n], 0, 0, 0);
    __builtin_amdgcn_s_setprio(0);
    __builtin_amdgcn_s_barrier();
    __builtin_amdgcn_sched_barrier(0);
    cur = (cur == 2) ? 0 : cur + 1;
  }
#undef GSTAGE64
  long r0 = (long)bm * 64 + wm + grp * 4;
  int c0 = bn * 128 + wn + col;
#pragma unroll
  for (int m = 0; m < 2; m++)
#pragma unroll
    for (int rr = 0; rr < 4; rr++) {
      long row = r0 + m * 16 + rr;
      if (row < 4160) {
#pragma unroll
        for (int n = 0; n < 4; n++)
          T[row * 1024 + c0 + n * 16] += acc[m][n][rr];
      }
    }
}

// ------- fused flash attention: 64-row i-tiles, no-max softmax, ones-column MFMA row-sum,
//         swizzled LDS, T4 counted-vmcnt 2-buffer pipeline, XCD-chunked flat grid -------
__global__ __launch_bounds__(256) void attn_k(
    const u16* __restrict__ qkv, const u16* __restrict__ vt,
    u16* __restrict__ out) {
  int nwg = gridDim.x;
  int id = blockIdx.x;
  int q = nwg >> 3, r = nwg & 7;
  int xcd = id & 7, off = id >> 3;
  int wgid = (xcd < r ? xcd * (q + 1) : r * (q + 1) + (xcd - r) * q) + off;
  int bh = wgid / 17, it = wgid % 17;
  int b = bh >> 4, h = bh & 15;
  int tid = threadIdx.x, wave = tid >> 6, lane = tid & 63;
  int col = lane & 15, grp = lane >> 4;
  int i0 = it * 64;
  int jmax = (it == 16) ? 1040 : 1024;
  const u16* qb = qkv + (long)b * 1040 * 3072 + h * 64;
  const u16* kb = qkv + (long)b * 1040 * 3072 + 1024 + h * 64;
  const u16* vb = vt + (long)bh * 64 * 1040;
  __shared__ u16 Ks[2][64 * 64];
  __shared__ u16 Vs[2][64 * 64];
  __shared__ u16 Ps[4][16 * 64];

  int srow0 = wave * 8 + (lane >> 3);
  int gsw = ((lane & 7) ^ (srow0 & 7)) * 8;
#define ASTAGE(buf, j0s) do { \
    int jv = (j0s) + gsw; if (jv >= 1040) jv = 1032; \
    _Pragma("unroll") \
    for (int qq = 0; qq < 2; qq++) { \
      int rr = qq * 32 + srow0; \
      gld16(kb + (long)((j0s) + rr) * 3072 + gsw, &Ks[buf][qq * 2048 + wave * 512]); \
      gld16(vb + (long)rr * 1040 + jv, &Vs[buf][qq * 2048 + wave * 512]); \
    } } while (0)

  short8 aq[2];
  int qrow = i0 + wave * 16;
#pragma unroll
  for (int kf = 0; kf < 2; kf++)
    aq[kf] = *(const short8*)(qb + (long)(qrow + col) * 3072 + kf * 32 + grp * 8);

  short8 one8 = {};
  if (col == 0) {
#pragma unroll
    for (int i = 0; i < 8; i++) one8[i] = (short)0x3F80;   // bf16 1.0
  }

  f32x4 oa[4] = {};
  f32x4 oa1 = {};

  ASTAGE(0, 0);
  int cur = 0;
  for (int j0 = 0; j0 < jmax; j0 += 64) {
    if (j0 + 64 < jmax) {
      ASTAGE(cur ^ 1, j0 + 64);
      asm volatile("s_waitcnt vmcnt(4)" ::: "memory");
    } else {
      asm volatile("s_waitcnt vmcnt(0)" ::: "memory");
    }
    __builtin_amdgcn_s_barrier();
    __builtin_amdgcn_sched_barrier(0);
    f32x4 s[4] = {};
#pragma unroll
    for (int kf = 0; kf < 2; kf++) {
      short8 bk[4];
#pragma unroll
      for (int n = 0; n < 4; n++) {
        int rk = n * 16 + col;
        bk[n] = *(const short8*)&Ks[cur][rk * 64 + ((kf * 32 + grp * 8) ^ ((rk & 7) << 3))];
      }
      __builtin_amdgcn_s_setprio(1);
#pragma unroll
      for (int n = 0; n < 4; n++)
        s[n] = __builtin_amdgcn_mfma_f32_16x16x32_bf16(aq[kf], bk[n], s[n], 0, 0, 0);
      __builtin_amdgcn_s_setprio(0);
    }
    if (j0 + 64 > jmax) {
      int lim = jmax - j0;
#pragma unroll
      for (int n = 0; n < 4; n++) {
        if (n * 16 + col >= lim) {
#pragma unroll
          for (int r2 = 0; r2 < 4; r2++) s[n][r2] = -1e30f;
        }
      }
    }
#pragma unroll
    for (int r2 = 0; r2 < 4; r2++) {
      int rp = grp * 4 + r2;
#pragma unroll
      for (int n = 0; n < 4; n++) {
        float p = __expf(s[n][r2]);
        Ps[wave][rp * 64 + ((n * 16 + col) ^ ((rp & 7) << 3))] = f2b(p);
      }
    }
#pragma unroll
    for (int kf = 0; kf < 2; kf++) {
      short8 ap, bv[4];
      int rm = col;
      ap = *(const short8*)&Ps[wave][rm * 64 + ((kf * 32 + grp * 8) ^ ((rm & 7) << 3))];
#pragma unroll
      for (int n = 0; n < 4; n++) {
        int rv = n * 16 + col;
        bv[n] = *(const short8*)&Vs[cur][rv * 64 + ((kf * 32 + grp * 8) ^ ((rv & 7) << 3))];
      }
      __builtin_amdgcn_s_setprio(1);
#pragma unroll
      for (int n = 0; n < 4; n++)
        oa[n] = __builtin_amdgcn_mfma_f32_16x16x32_bf16(ap, bv[n], oa[n], 0, 0, 0);
      oa1 = __builtin_amdgcn_mfma_f32_16x16x32_bf16(ap, one8, oa1, 0, 0, 0);
      __builtin_amdgcn_s_setprio(0);
    }
    __builtin_amdgcn_s_barrier();
    __builtin_amdgcn_sched_barrier(0);
    cur ^= 1;
  }
#undef ASTAGE
  float lr[4];
#pragma unroll
  for (int r2 = 0; r2 < 4; r2++) lr[r2] = __shfl(oa1[r2], lane & 48, 64);
#pragma unroll
  for (int n = 0; n < 4; n++)
#pragma unroll
    for (int r2 = 0; r2 < 4; r2++) {
      int i = i0 + wave * 16 + grp * 4 + r2;
      if (i < 1040)
        out[((long)b * 1040 + i) * 1024 + h * 64 + n * 16 + col] = f2b(oa[n][r2] / lr[r2]);
    }
}

// ---------------- weighted column sum for token-mean pooling ----------------
__global__ __launch_bounds__(256) void wcolsum_k(
    const float* __restrict__ t, const float* __restrict__ rowm,
    const float* __restrict__ rinv, float* __restrict__ colsum,
    float* __restrict__ msum) {
  int b = blockIdx.x, c = blockIdx.y, tid = threadIdx.x;
  float a0 = 0, a1 = 0, a2 = 0, a3 = 0, ms = 0;
  for (int r = 0; r < 20; r++) {
    long row = (long)b * 1040 + c * 20 + r;
    float iv = rinv[row];
    float4 v = ((const float4*)(t + row * 1024))[tid];
    a0 += v.x * iv; a1 += v.y * iv; a2 += v.z * iv; a3 += v.w * iv;
    if (tid == 0) ms += rowm[row] * iv;
  }
  atomicAdd(&colsum[b * 1024 + tid * 4 + 0], a0);
  atomicAdd(&colsum[b * 1024 + tid * 4 + 1], a1);
  atomicAdd(&colsum[b * 1024 + tid * 4 + 2], a2);
  atomicAdd(&colsum[b * 1024 + tid * 4 + 3], a3);
  if (tid == 0) atomicAdd(&msum[b], ms);
}

// ---------------- pooled matvec 1: tmp = mean @ pWkv_v ----------------
__global__ __launch_bounds__(256) void mv1_k(
    const float* __restrict__ colsum, const float* __restrict__ msum,
    const float* __restrict__ g, const float* __restrict__ pWkv,
    float* __restrict__ tmp) {
  int b = blockIdx.x, n = blockIdx.y * 256 + threadIdx.x;
  float msb = msum[b];
  float acc = 0.f;
  for (int k = 0; k < 1024; k++) {
    float mk = g[k] * (colsum[b * 1024 + k] - msb);
    acc += mk * pWkv[(long)k * 2048 + 1024 + n];
  }
  tmp[b * 1024 + n] = acc * (1.f / 1040.f);
}

// ---------------- pooled matvec 2 + assemble spliced/fusion ----------------
__global__ __launch_bounds__(256) void mv2_k(
    const float* __restrict__ tmp, const float* __restrict__ pWo,
    const float* __restrict__ ret, float* __restrict__ spl,
    float* __restrict__ fub) {
  int b = blockIdx.x, n = blockIdx.y * 256 + threadIdx.x;
  float acc = 0.f;
  for (int k = 0; k < 1024; k++) acc += tmp[b * 1024 + k] * pWo[(long)k * 1024 + n];
  spl[b * 1024 + n] = ret[n] + acc;
  fub[b * 1024 + n] = ret[1024 + n] + acc;
}

// ---------------- contrastive loss ----------------
__device__ float closs_dev(const float L[4][4]) {
  float la = 0.f, lb = 0.f;
  for (int i = 0; i < 4; i++) {
    float mx = fmaxf(fmaxf(L[i][0], L[i][1]), fmaxf(L[i][2], L[i][3]));
    float sm = expf(L[i][0] - mx) + expf(L[i][1] - mx) + expf(L[i][2] - mx) + expf(L[i][3] - mx);
    la += mx + logf(sm) - L[i][i];
  }
  for (int j = 0; j < 4; j++) {
    float mx = fmaxf(fmaxf(L[0][j], L[1][j]), fmaxf(L[2][j], L[3][j]));
    float sm = expf(L[0][j] - mx) + expf(L[1][j] - mx) + expf(L[2][j] - mx) + expf(L[3][j] - mx);
    lb += mx + logf(sm) - L[j][j];
  }
  return 0.125f * (la + lb);  // ((la/4)+(lb/4))*0.5
}

__global__ __launch_bounds__(256) void loss_k(
    const float* __restrict__ s, const float* __restrict__ f,
    const float* __restrict__ lsc, const float* __restrict__ lsf,
    float* __restrict__ out) {
  __shared__ float dots[36];
  int tid = threadIdx.x, wave = tid >> 6, lane = tid & 63;
  for (int d = wave; d < 36; d += 4) {
    const float *a, *bb;
    if (d < 16) { a = s + (d >> 2) * 1024; bb = s + (d & 3) * 1024; }
    else if (d < 32) { int e = d - 16; a = s + (e >> 2) * 1024; bb = f + (e & 3) * 1024; }
    else { a = f + (d - 32) * 1024; bb = a; }
    float p = 0.f;
    for (int k = lane; k < 1024; k += 64) p += a[k] * bb[k];
#pragma unroll
    for (int o = 32; o > 0; o >>= 1) p += __shfl_xor(p, o, 64);
    if (lane == 0) dots[d] = p;
  }
  __syncthreads();
  if (tid == 0) {
    float nS[4], nF[4];
    for (int i = 0; i < 4; i++) { nS[i] = sqrtf(dots[i * 4 + i]); nF[i] = sqrtf(dots[32 + i]); }
    float e1 = expf(lsc[0]), e2 = expf(lsf[0]);
    float L1[4][4], L2[4][4];
    for (int i = 0; i < 4; i++)
      for (int j = 0; j < 4; j++) {
        L1[i][j] = e1 * dots[i * 4 + j] / (nS[i] * nS[j]);
        L2[i][j] = e2 * dots[16 + i * 4 + j] / (nS[i] * nF[j]);
      }
    out[0] = closs_dev(L1) + closs_dev(L2);
  }
}

extern "C" void kernel_launch(void* const* d_in, const int* in_sizes, int n_in,
                              void* d_out, int out_size, void* d_ws, size_t ws_size,
                              hipStream_t stream) {
  (void)in_sizes; (void)n_in; (void)out_size; (void)ws_size;
  const float* sdata = (const float*)d_in[0];
  const int*   sidx  = (const int*)d_in[1];
  const float* emb   = (const float*)d_in[2];
  const float* fus   = (const float*)d_in[3];
  const float* ret   = (const float*)d_in[4];
  const float* ln1g  = (const float*)d_in[5];
  const float* Wq    = (const float*)d_in[6];
  const float* Wkv   = (const float*)d_in[7];
  const float* Wo    = (const float*)d_in[8];
  const float* ln2g  = (const float*)d_in[9];
  const float* Wff1  = (const float*)d_in[10];
  const float* Wff2  = (const float*)d_in[11];
  const float* normg = (const float*)d_in[12];
  const float* pWkv  = (const float*)d_in[15];
  const float* pWo   = (const float*)d_in[16];
  const float* lsc   = (const float*)d_in[17];
  const float* lsf   = (const float*)d_in[18];

  char* ws = (char*)d_ws;
  float* t   = (float*)(ws + 0L);                // 4224*1024*4  = 17,301,504
  u16* xn    = (u16*)(ws + 17301504L);           // 4224*1024*2  =  8,650,752
  char* U    = ws + 25952256L;
  u16* qkv   = (u16*)(U);                        // 4352*3072*2  = 26,738,688
  u16* vtb   = (u16*)(U + 26738688L);            // 64*64*1040*2 + pad = 8,531,968
  u16* aout  = (u16*)(U + 35270656L);            // 4224*1024*2 (attn out; dead after Wo GEMM)
  u16* ab    = (u16*)(U + 35270656L);            // 4224*2752*2 = 23,248,896 (swiglu out; reuses aout slot)
  char* WT   = ws + 95698944L;                   // per-layer weights (25,296,896), reused (L3-hot)
  u16* qkvT  = (u16*)(WT);                       // 3072*1024*2
  u16* WoT   = (u16*)(WT + 6291456L);            // 1024*1024*2
  u16* f1T   = (u16*)(WT + 8388608L);            // 5504*1024*2 (column-permuted swiglu layout)
  u16* f2T   = (u16*)(WT + 19660800L);           // 1024*2752*2
  char* FIN  = ws + 120995840L;
  float* rowm   = (float*)(FIN);
  float* rinvp  = (float*)(FIN + 16640L);
  float* colsum = (float*)(FIN + 33280L);
  float* msum   = (float*)(FIN + 49664L);
  float* tmp    = (float*)(FIN + 49728L);
  float* spl    = (float*)(FIN + 66112L);
  float* fub    = (float*)(FIN + 82496L);

  embed_k<<<4160, 256, 0, stream>>>(sdata, sidx, emb, fus, t);

  for (int l = 0; l < 6; l++) {
    wtrans5_k<<<12352, 256, 0, stream>>>(
        Wq + (long)l * 1024 * 1024, Wkv + (long)l * 1024 * 2048,
        Wo + (long)l * 1024 * 1024, Wff1 + (long)l * 1024 * 5460,
        Wff2 + (long)l * 2730 * 1024, qkvT, WoT, f1T, f2T);

    ln_k<<<4160, 256, 0, stream>>>(t, ln1g + l * 1024, xn);
    // qkv GEMM (mode 2): writes qkv + fused V-transpose into vtb
    gemm_bt<<<33 * 24, 256, 0, stream>>>(xn, 1024, qkvT, 1024, qkv, 3072, 1024, 2, 33, vtb);
    attn_k<<<1088, 256, 0, stream>>>(qkv, vtb, aout);
    // Wo GEMM (64x128 tiles): t += aout @ WoT^T  (exclusive-ownership RMW)
    gemm64_rmw<<<66 * 8, 256, 0, stream>>>(aout, 1024, WoT, 1024, t, 1024, 66);
    ln_k<<<4160, 256, 0, stream>>>(t, ln2g + l * 1024, xn);
    // ff1 GEMM (mode 3): fused SwiGLU epilogue -> ab directly
    gemm_bt<<<33 * 43, 256, 0, stream>>>(xn, 1024, f1T, 1024, ab, 2752, 1024, 3, 33, vtb);
    // ff2 GEMM (64x128 tiles): t += ab @ f2T^T
    gemm64_rmw<<<66 * 8, 256, 0, stream>>>(ab, 2752, f2T, 2752, t, 2752, 66);
  }

  rowstats_k<<<4160, 256, 0, stream>>>(t, rowm, rinvp);
  hipMemsetAsync(colsum, 0, 16448, stream);  // colsum + msum
  wcolsum_k<<<dim3(4, 52), 256, 0, stream>>>(t, rowm, rinvp, colsum, msum);
  mv1_k<<<dim3(4, 4), 256, 0, stream>>>(colsum, msum, normg, pWkv, tmp);
  mv2_k<<<dim3(4, 4), 256, 0, stream>>>(tmp, pWo, ret, spl, fub);
  loss_k<<<1, 256, 0, stream>>>(spl, fub, lsc, lsf, (float*)d_out);
}

// Round 15
// 1896.352 us; speedup vs baseline: 1.0191x; 1.0191x over previous
//
#include <hip/hip_runtime.h>

typedef unsigned short u16;
typedef unsigned long long u64;
typedef __attribute__((ext_vector_type(8))) short short8;
typedef __attribute__((ext_vector_type(4))) float f32x4;

__device__ __forceinline__ u16 f2b(float f) {
  union { float f; unsigned u; } x; x.f = f;
  unsigned r = x.u + 0x7fffu + ((x.u >> 16) & 1u);
  return (u16)(r >> 16);
}
__device__ __forceinline__ float b2f(u16 h) {
  union { unsigned u; float f; } x; x.u = ((unsigned)h) << 16;
  return x.f;
}
__device__ __forceinline__ void gld16(const void* g, void* l) {
  __builtin_amdgcn_global_load_lds(
      (__attribute__((address_space(1))) const void*)g,
      (__attribute__((address_space(3))) void*)l, 16, 0, 0);
}

// ---------------- embedding: t[b,n,:] = emb[idx]*data or fusion ----------------
__global__ __launch_bounds__(256) void embed_k(
    const float* __restrict__ data, const int* __restrict__ idx,
    const float* __restrict__ emb, const float* __restrict__ fus,
    float* __restrict__ t) {
  int row = blockIdx.x;            // 0..4159
  int b = row / 1040, n = row % 1040;
  int tid = threadIdx.x;
  const float4* src;
  float sc = 1.f;
  if (n < 1024) {
    int e = idx[b * 1024 + n];
    sc = data[b * 1024 + n];
    src = (const float4*)(emb + (long)e * 1024);
  } else {
    src = (const float4*)(fus + (long)(n - 1024) * 1024);
  }
  float4 v = src[tid];
  v.x *= sc; v.y *= sc; v.z *= sc; v.w *= sc;
  ((float4*)(t + (long)row * 1024))[tid] = v;
}

// ------------- fused 5-matrix weight transpose: f32 src[K][N] -> bf16 dst[Npad][Kpad]
//               f1T gets COLUMN-PERMUTED layout: new col nc (p=nc>>5,sub=nc&31):
//               sub<16 -> xh col p*16+sub ; sub>=16 -> gate col 2714+p*16+sub  -------------
__global__ __launch_bounds__(256) void wtrans5_k(
    const float* __restrict__ sWq, const float* __restrict__ sWkv,
    const float* __restrict__ sWo, const float* __restrict__ sW1,
    const float* __restrict__ sW2,
    u16* __restrict__ dQkvT, u16* __restrict__ dWoT,
    u16* __restrict__ dF1T, u16* __restrict__ dF2T) {
  int id = blockIdx.x;
  const float* src; u16* dst; int K, N, Kpad, nx; float sc = 1.f; int perm = 0;
  if (id < 1024)       { src = sWq;  dst = dQkvT;             K = 1024; N = 1024; Kpad = 1024; nx = 32; sc = 0.125f; }
  else if (id < 3072)  { id -= 1024; src = sWkv; dst = dQkvT + 1024 * 1024; K = 1024; N = 2048; Kpad = 1024; nx = 64; }
  else if (id < 4096)  { id -= 3072; src = sWo;  dst = dWoT;  K = 1024; N = 1024; Kpad = 1024; nx = 32; }
  else if (id < 9600)  { id -= 4096; src = sW1;  dst = dF1T;  K = 1024; N = 5504; Kpad = 1024; nx = 172; perm = 1; }
  else                 { id -= 9600; src = sW2;  dst = dF2T;  K = 2730; N = 1024; Kpad = 2752; nx = 32; }
  int n0 = (id % nx) * 32, k0 = (id / nx) * 32;
  __shared__ float tile[32][33];
  int x = threadIdx.x & 31, y = threadIdx.x >> 5;
#pragma unroll
  for (int i = 0; i < 4; i++) {
    int k = k0 + y + i * 8, n = n0 + x;
    float val = 0.f;
    if (perm) {
      int p = n >> 5, sub = n & 31;
      int o = (sub < 16) ? (p * 16 + sub) : (2714 + p * 16 + sub);
      bool ok = (sub < 16) ? (o < 2730) : (o < 5460);
      val = (k < K && ok) ? src[(long)k * 5460 + o] : 0.f;
    } else {
      val = (k < K && n < N) ? src[(long)k * N + n] * sc : 0.f;
    }
    tile[y + i * 8][x] = val;
  }
  __syncthreads();
#pragma unroll
  for (int i = 0; i < 4; i++) {
    int n = n0 + y + i * 8, k = k0 + x;
    dst[(long)n * Kpad + k] = f2b(tile[x][y + i * 8]);
  }
}

// ---------------- LayerNorm (biased var, eps 1e-5) -> bf16 ----------------
__global__ __launch_bounds__(256) void ln_k(
    const float* __restrict__ t, const float* __restrict__ g,
    u16* __restrict__ xn) {
  int row = blockIdx.x, tid = threadIdx.x;
  int wave = tid >> 6, lane = tid & 63;
  float4 v = ((const float4*)(t + (long)row * 1024))[tid];
  float s = v.x + v.y + v.z + v.w;
#pragma unroll
  for (int o = 32; o > 0; o >>= 1) s += __shfl_xor(s, o, 64);
  __shared__ float r1[4], r2[4];
  if (lane == 0) r1[wave] = s;
  __syncthreads();
  float mean = (r1[0] + r1[1] + r1[2] + r1[3]) * (1.f / 1024.f);
  float dx = v.x - mean, dy = v.y - mean, dz = v.z - mean, dw = v.w - mean;
  float q = dx * dx + dy * dy + dz * dz + dw * dw;
#pragma unroll
  for (int o = 32; o > 0; o >>= 1) q += __shfl_xor(q, o, 64);
  if (lane == 0) r2[wave] = q;
  __syncthreads();
  float var = (r2[0] + r2[1] + r2[2] + r2[3]) * (1.f / 1024.f);
  float inv = rsqrtf(var + 1e-5f);
  float4 gv = ((const float4*)g)[tid];
  u64 pack = (u64)f2b(dx * inv * gv.x)
           | ((u64)f2b(dy * inv * gv.y) << 16)
           | ((u64)f2b(dz * inv * gv.z) << 32)
           | ((u64)f2b(dw * inv * gv.w) << 48);
  *(u64*)(xn + (long)row * 1024 + tid * 4) = pack;
}

// ------- fused reduce(t += p0+p1) + LayerNorm -> bf16 -------
__global__ __launch_bounds__(256) void lnred_k(
    float* __restrict__ t, const float* __restrict__ p0, const float* __restrict__ p1,
    const float* __restrict__ g, u16* __restrict__ xn) {
  int row = blockIdx.x, tid = threadIdx.x;
  int wave = tid >> 6, lane = tid & 63;
  long base = (long)row * 1024;
  float4 v = ((const float4*)(t + base))[tid];
  float4 a = ((const float4*)(p0 + base))[tid];
  float4 bq = ((const float4*)(p1 + base))[tid];
  v.x += a.x + bq.x; v.y += a.y + bq.y; v.z += a.z + bq.z; v.w += a.w + bq.w;
  ((float4*)(t + base))[tid] = v;
  float s = v.x + v.y + v.z + v.w;
#pragma unroll
  for (int o = 32; o > 0; o >>= 1) s += __shfl_xor(s, o, 64);
  __shared__ float r1[4], r2[4];
  if (lane == 0) r1[wave] = s;
  __syncthreads();
  float mean = (r1[0] + r1[1] + r1[2] + r1[3]) * (1.f / 1024.f);
  float dx = v.x - mean, dy = v.y - mean, dz = v.z - mean, dw = v.w - mean;
  float q = dx * dx + dy * dy + dz * dz + dw * dw;
#pragma unroll
  for (int o = 32; o > 0; o >>= 1) q += __shfl_xor(q, o, 64);
  if (lane == 0) r2[wave] = q;
  __syncthreads();
  float var = (r2[0] + r2[1] + r2[2] + r2[3]) * (1.f / 1024.f);
  float inv = rsqrtf(var + 1e-5f);
  float4 gv = ((const float4*)g)[tid];
  u64 pack = (u64)f2b(dx * inv * gv.x)
           | ((u64)f2b(dy * inv * gv.y) << 16)
           | ((u64)f2b(dz * inv * gv.z) << 32)
           | ((u64)f2b(dw * inv * gv.w) << 48);
  *(u64*)(xn + base + tid * 4) = pack;
}

// ------- fused reduce(t += p0+p1) + final-LN row stats -------
__global__ __launch_bounds__(256) void redrow_k(
    float* __restrict__ t, const float* __restrict__ p0, const float* __restrict__ p1,
    float* __restrict__ rowm, float* __restrict__ rinv) {
  int row = blockIdx.x, tid = threadIdx.x;
  int wave = tid >> 6, lane = tid & 63;
  long base = (long)row * 1024;
  float4 v = ((const float4*)(t + base))[tid];
  float4 a = ((const float4*)(p0 + base))[tid];
  float4 bq = ((const float4*)(p1 + base))[tid];
  v.x += a.x + bq.x; v.y += a.y + bq.y; v.z += a.z + bq.z; v.w += a.w + bq.w;
  ((float4*)(t + base))[tid] = v;
  float s = v.x + v.y + v.z + v.w;
#pragma unroll
  for (int o = 32; o > 0; o >>= 1) s += __shfl_xor(s, o, 64);
  __shared__ float r1[4], r2[4];
  if (lane == 0) r1[wave] = s;
  __syncthreads();
  float mean = (r1[0] + r1[1] + r1[2] + r1[3]) * (1.f / 1024.f);
  float dx = v.x - mean, dy = v.y - mean, dz = v.z - mean, dw = v.w - mean;
  float q = dx * dx + dy * dy + dz * dz + dw * dw;
#pragma unroll
  for (int o = 32; o > 0; o >>= 1) q += __shfl_xor(q, o, 64);
  if (lane == 0) r2[wave] = q;
  __syncthreads();
  if (tid == 0) {
    float var = (r2[0] + r2[1] + r2[2] + r2[3]) * (1.f / 1024.f);
    rowm[row] = mean;
    rinv[row] = rsqrtf(var + 1e-5f);
  }
}

// ------- GEMM: C[M][N] = A[M][K](bf16) * Bt[N][K](bf16)^T, tile 128x128, BK=32
// mode0: bf16 store; mode1: f32 store to partial ksp; mode2: bf16 + fused V-transpose;
// mode3: fused SwiGLU epilogue (permuted f1T; writes gelu(gate)*xh to C[ldc=2752])
// T4 counted-vmcnt 3-deep pipeline; T2 XOR-swizzled LDS; bijective-XCD-swizzled 1D grid.
__global__ __launch_bounds__(256) void gemm_bt(
    const u16* __restrict__ A, int lda,
    const u16* __restrict__ Bt, int ldb,
    void* __restrict__ C, int ldc,
    int K, int mode, int gx, int ns, long pstride, u16* __restrict__ vt) {
  __shared__ u16 As[3][128 * 32];
  __shared__ u16 Bs[3][128 * 32];
  int tid = threadIdx.x;
  int wave = tid >> 6, lane = tid & 63;
  int col = lane & 15, grp = lane >> 4;
  // bijective XCD swizzle (m204)
  int nwg = gridDim.x;
  int id = blockIdx.x;
  int q = nwg >> 3, r = nwg & 7;
  int xcd = id & 7, off = id >> 3;
  int wgid = (xcd < r ? xcd * (q + 1) : r * (q + 1) + (xcd - r) * q) + off;
  int tiles = nwg / ns;
  int ksp = wgid / tiles;
  int rem = wgid % tiles;
  int bm = rem % gx, bn = rem / gx;
  int nst = K >> 5;
  int k0 = ((nst * ksp) / ns) << 5;
  int k1 = ((nst * (ksp + 1)) / ns) << 5;
  int sr = wave * 16 + (lane >> 2);
  // T2: pre-swizzled source k-chunk; LDS row r stores global chunk s^((r>>1)&3) at slot s.
  int sk = ((lane & 3) ^ ((lane >> 3) & 3)) * 8;
  const u16* aSrc = A + ((long)bm * 128 + sr) * lda + sk;
  const u16* bSrc = Bt + ((long)bn * 128 + sr) * ldb + sk;
  int wm = (wave >> 1) * 64, wn = (wave & 1) * 64;
  f32x4 acc[4][4] = {};

#define GSTAGE(buf, kt) do { \
    _Pragma("unroll") \
    for (int qq = 0; qq < 2; qq++) { \
      gld16(aSrc + (kt) + (long)qq * 64 * lda, &As[buf][wave * 512 + qq * 2048]); \
      gld16(bSrc + (kt) + (long)qq * 64 * ldb, &Bs[buf][wave * 512 + qq * 2048]); \
    } } while (0)

  // prologue: stage tiles 0 and 1 (4 vmem ops each)
  GSTAGE(0, k0);
  if (k0 + 32 < k1) GSTAGE(1, k0 + 32);
  int cur = 0;
  int slot = (grp ^ ((col >> 1) & 3)) * 8;     // swizzled read slot (u16)
  for (int kt = k0; kt < k1; kt += 32) {
    if (kt + 64 < k1) {
      int nb = cur + 2; if (nb >= 3) nb -= 3;
      GSTAGE(nb, kt + 64);
      asm volatile("s_waitcnt vmcnt(8)" ::: "memory");   // stage t done; t+1,t+2 in flight
    } else if (kt + 32 < k1) {
      asm volatile("s_waitcnt vmcnt(4)" ::: "memory");   // stage t done; t+1 in flight
    } else {
      asm volatile("s_waitcnt vmcnt(0)" ::: "memory");   // last tile
    }
    __builtin_amdgcn_s_barrier();                        // stage t visible to all waves
    __builtin_amdgcn_sched_barrier(0);                   // no ds_read hoisting (rule #18)
    short8 af[4], bfv[4];
#pragma unroll
    for (int m = 0; m < 4; m++)
      af[m] = *(const short8*)&As[cur][(wm + m * 16 + col) * 32 + slot];
#pragma unroll
    for (int n = 0; n < 4; n++)
      bfv[n] = *(const short8*)&Bs[cur][(wn + n * 16 + col) * 32 + slot];
    __builtin_amdgcn_s_setprio(1);
#pragma unroll
    for (int m = 0; m < 4; m++)
#pragma unroll
      for (int n = 0; n < 4; n++)
        acc[m][n] = __builtin_amdgcn_mfma_f32_16x16x32_bf16(af[m], bfv[n], acc[m][n], 0, 0, 0);
    __builtin_amdgcn_s_setprio(0);
    __builtin_amdgcn_s_barrier();                        // all reads of buf[cur] done
    __builtin_amdgcn_sched_barrier(0);                   // no gld16 sinking above barrier
    cur = (cur == 2) ? 0 : cur + 1;
  }
#undef GSTAGE
  long r0 = (long)bm * 128 + wm + grp * 4;
  int c0 = bn * 128 + wn + col;
  if (mode == 3) {
    // fused SwiGLU: fragment n even = xh block p, n odd = gate block p (same p)
    u16* Ab = (u16*)C;
#pragma unroll
    for (int m = 0; m < 4; m++)
#pragma unroll
      for (int np = 0; np < 2; np++) {
        int ac = ((bn * 4 + (wn >> 5) + np) << 4) + col;   // original pair index
#pragma unroll
        for (int rr = 0; rr < 4; rr++) {
          float xh = acc[m][np * 2][rr];
          float gt = acc[m][np * 2 + 1][rr];
          float rv = 0.f;
          if (ac < 2730)
            rv = 0.5f * gt * (1.f + erff(gt * 0.70710678118f)) * xh;
          Ab[(r0 + m * 16 + rr) * ldc + ac] = f2b(rv);
        }
      }
  } else if (mode != 1) {
    u16* Cb = (u16*)C;
#pragma unroll
    for (int m = 0; m < 4; m++)
#pragma unroll
      for (int n = 0; n < 4; n++)
#pragma unroll
        for (int rr = 0; rr < 4; rr++)
          Cb[(r0 + m * 16 + rr) * ldc + c0 + n * 16] = f2b(acc[m][n][rr]);
    if (mode == 2 && bn >= 16) {
      // fused V-transpose: vt[(b*16+h)*64 + d][j] = C[row=b*1040+j][2048 + h*64 + d]
#pragma unroll
      for (int m = 0; m < 4; m++) {
        long row = r0 + m * 16;                 // 4-aligned; 4 consecutive j in same b
        if (row < 4160) {
          int bidx = (int)(row / 1040);
          int j = (int)(row - (long)bidx * 1040);
#pragma unroll
          for (int n = 0; n < 4; n++) {
            int d = c0 + n * 16 - 2048;
            u64 pack = (u64)f2b(acc[m][n][0])
                     | ((u64)f2b(acc[m][n][1]) << 16)
                     | ((u64)f2b(acc[m][n][2]) << 32)
                     | ((u64)f2b(acc[m][n][3]) << 48);
            *(u64*)(vt + ((long)(bidx * 16 + (d >> 6)) * 64 + (d & 63)) * 1040 + j) = pack;
          }
        }
      }
    }
  } else {
    float* Cf = (float*)C + (long)ksp * pstride;
#pragma unroll
    for (int m = 0; m < 4; m++)
#pragma unroll
      for (int n = 0; n < 4; n++)
#pragma unroll
        for (int rr = 0; rr < 4; rr++)
          Cf[(r0 + m * 16 + rr) * ldc + c0 + n * 16] = acc[m][n][rr];
  }
}

// ------- fused flash attention: 64-row i-tiles, no-max softmax, ones-column MFMA row-sum,
//         swizzled LDS, T4 counted-vmcnt 2-buffer pipeline, XCD-chunked flat grid -------
__global__ __launch_bounds__(256) void attn_k(
    const u16* __restrict__ qkv, const u16* __restrict__ vt,
    u16* __restrict__ out) {
  int nwg = gridDim.x;
  int id = blockIdx.x;
  int q = nwg >> 3, r = nwg & 7;
  int xcd = id & 7, off = id >> 3;
  int wgid = (xcd < r ? xcd * (q + 1) : r * (q + 1) + (xcd - r) * q) + off;
  int bh = wgid / 17, it = wgid % 17;
  int b = bh >> 4, h = bh & 15;
  int tid = threadIdx.x, wave = tid >> 6, lane = tid & 63;
  int col = lane & 15, grp = lane >> 4;
  int i0 = it * 64;
  int jmax = (it == 16) ? 1040 : 1024;
  const u16* qb = qkv + (long)b * 1040 * 3072 + h * 64;
  const u16* kb = qkv + (long)b * 1040 * 3072 + 1024 + h * 64;
  const u16* vb = vt + (long)bh * 64 * 1040;
  __shared__ u16 Ks[2][64 * 64];
  __shared__ u16 Vs[2][64 * 64];
  __shared__ u16 Ps[4][16 * 64];

  int srow0 = wave * 8 + (lane >> 3);                 // row within 32-row half
  int gsw = ((lane & 7) ^ (srow0 & 7)) * 8;           // swizzled source col (u16)
#define ASTAGE(buf, j0s) do { \
    int jv = (j0s) + gsw; if (jv >= 1040) jv = 1032; \
    _Pragma("unroll") \
    for (int qq = 0; qq < 2; qq++) { \
      int rr = qq * 32 + srow0; \
      gld16(kb + (long)((j0s) + rr) * 3072 + gsw, &Ks[buf][qq * 2048 + wave * 512]); \
      gld16(vb + (long)rr * 1040 + jv, &Vs[buf][qq * 2048 + wave * 512]); \
    } } while (0)

  short8 aq[2];
  int qrow = i0 + wave * 16;
#pragma unroll
  for (int kf = 0; kf < 2; kf++)
    aq[kf] = *(const short8*)(qb + (long)(qrow + col) * 3072 + kf * 32 + grp * 8);

  short8 one8 = {};
  if (col == 0) {
#pragma unroll
    for (int i = 0; i < 8; i++) one8[i] = (short)0x3F80;   // bf16 1.0
  }

  f32x4 oa[4] = {};
  f32x4 oa1 = {};                                          // ones-column: row-sums in col 0

  ASTAGE(0, 0);           // 4 vmem ops
  int cur = 0;
  for (int j0 = 0; j0 < jmax; j0 += 64) {
    if (j0 + 64 < jmax) {
      ASTAGE(cur ^ 1, j0 + 64);                         // issue next tile (4 ops)
      asm volatile("s_waitcnt vmcnt(4)" ::: "memory");  // tile t landed; t+1 in flight
    } else {
      asm volatile("s_waitcnt vmcnt(0)" ::: "memory");  // last tile
    }
    __builtin_amdgcn_s_barrier();                       // tile t visible to all waves
    __builtin_amdgcn_sched_barrier(0);                  // no ds_read hoisting (rule #18)
    f32x4 s[4] = {};
#pragma unroll
    for (int kf = 0; kf < 2; kf++) {
      short8 bk[4];
#pragma unroll
      for (int n = 0; n < 4; n++) {
        int rk = n * 16 + col;
        bk[n] = *(const short8*)&Ks[cur][rk * 64 + ((kf * 32 + grp * 8) ^ ((rk & 7) << 3))];
      }
      __builtin_amdgcn_s_setprio(1);
#pragma unroll
      for (int n = 0; n < 4; n++)
        s[n] = __builtin_amdgcn_mfma_f32_16x16x32_bf16(aq[kf], bk[n], s[n], 0, 0, 0);
      __builtin_amdgcn_s_setprio(0);
    }
    if (j0 + 64 > jmax) {
      int lim = jmax - j0;
#pragma unroll
      for (int n = 0; n < 4; n++) {
        if (n * 16 + col >= lim) {
#pragma unroll
          for (int r2 = 0; r2 < 4; r2++) s[n][r2] = -1e30f;
        }
      }
    }
    // no-max softmax (scores structurally bounded); row-sum comes from ones-MFMA below
#pragma unroll
    for (int r2 = 0; r2 < 4; r2++) {
      int rp = grp * 4 + r2;
#pragma unroll
      for (int n = 0; n < 4; n++) {
        float p = __expf(s[n][r2]);
        Ps[wave][rp * 64 + ((n * 16 + col) ^ ((rp & 7) << 3))] = f2b(p);
      }
    }
#pragma unroll
    for (int kf = 0; kf < 2; kf++) {
      short8 ap, bv[4];
      int rm = col;
      ap = *(const short8*)&Ps[wave][rm * 64 + ((kf * 32 + grp * 8) ^ ((rm & 7) << 3))];
#pragma unroll
      for (int n = 0; n < 4; n++) {
        int rv = n * 16 + col;
        bv[n] = *(const short8*)&Vs[cur][rv * 64 + ((kf * 32 + grp * 8) ^ ((rv & 7) << 3))];
      }
      __builtin_amdgcn_s_setprio(1);
#pragma unroll
      for (int n = 0; n < 4; n++)
        oa[n] = __builtin_amdgcn_mfma_f32_16x16x32_bf16(ap, bv[n], oa[n], 0, 0, 0);
      oa1 = __builtin_amdgcn_mfma_f32_16x16x32_bf16(ap, one8, oa1, 0, 0, 0);
      __builtin_amdgcn_s_setprio(0);
    }
    __builtin_amdgcn_s_barrier();                       // all reads of buf[cur] done
    __builtin_amdgcn_sched_barrier(0);                  // no gld16 sinking above barrier
    cur ^= 1;
  }
#undef ASTAGE
  float lr[4];
#pragma unroll
  for (int r2 = 0; r2 < 4; r2++) lr[r2] = __shfl(oa1[r2], lane & 48, 64);  // broadcast col-0 row-sum
#pragma unroll
  for (int n = 0; n < 4; n++)
#pragma unroll
    for (int r2 = 0; r2 < 4; r2++) {
      int i = i0 + wave * 16 + grp * 4 + r2;
      if (i < 1040)
        out[((long)b * 1040 + i) * 1024 + h * 64 + n * 16 + col] = f2b(oa[n][r2] / lr[r2]);
    }
}

// ---------------- weighted column sum for token-mean pooling ----------------
__global__ __launch_bounds__(256) void wcolsum_k(
    const float* __restrict__ t, const float* __restrict__ rowm,
    const float* __restrict__ rinv, float* __restrict__ colsum,
    float* __restrict__ msum) {
  int b = blockIdx.x, c = blockIdx.y, tid = threadIdx.x;
  float a0 = 0, a1 = 0, a2 = 0, a3 = 0, ms = 0;
  for (int r = 0; r < 20; r++) {
    long row = (long)b * 1040 + c * 20 + r;
    float iv = rinv[row];
    float4 v = ((const float4*)(t + row * 1024))[tid];
    a0 += v.x * iv; a1 += v.y * iv; a2 += v.z * iv; a3 += v.w * iv;
    if (tid == 0) ms += rowm[row] * iv;
  }
  atomicAdd(&colsum[b * 1024 + tid * 4 + 0], a0);
  atomicAdd(&colsum[b * 1024 + tid * 4 + 1], a1);
  atomicAdd(&colsum[b * 1024 + tid * 4 + 2], a2);
  atomicAdd(&colsum[b * 1024 + tid * 4 + 3], a3);
  if (tid == 0) atomicAdd(&msum[b], ms);
}

// ---------------- pooled matvec 1: tmp = mean @ pWkv_v ----------------
__global__ __launch_bounds__(256) void mv1_k(
    const float* __restrict__ colsum, const float* __restrict__ msum,
    const float* __restrict__ g, const float* __restrict__ pWkv,
    float* __restrict__ tmp) {
  int b = blockIdx.x, n = blockIdx.y * 256 + threadIdx.x;
  float msb = msum[b];
  float acc = 0.f;
  for (int k = 0; k < 1024; k++) {
    float mk = g[k] * (colsum[b * 1024 + k] - msb);
    acc += mk * pWkv[(long)k * 2048 + 1024 + n];
  }
  tmp[b * 1024 + n] = acc * (1.f / 1040.f);
}

// ---------------- pooled matvec 2 + assemble spliced/fusion ----------------
__global__ __launch_bounds__(256) void mv2_k(
    const float* __restrict__ tmp, const float* __restrict__ pWo,
    const float* __restrict__ ret, float* __restrict__ spl,
    float* __restrict__ fub) {
  int b = blockIdx.x, n = blockIdx.y * 256 + threadIdx.x;
  float acc = 0.f;
  for (int k = 0; k < 1024; k++) acc += tmp[b * 1024 + k] * pWo[(long)k * 1024 + n];
  spl[b * 1024 + n] = ret[n] + acc;
  fub[b * 1024 + n] = ret[1024 + n] + acc;
}

// ---------------- contrastive loss ----------------
__device__ float closs_dev(const float L[4][4]) {
  float la = 0.f, lb = 0.f;
  for (int i = 0; i < 4; i++) {
    float mx = fmaxf(fmaxf(L[i][0], L[i][1]), fmaxf(L[i][2], L[i][3]));
    float sm = expf(L[i][0] - mx) + expf(L[i][1] - mx) + expf(L[i][2] - mx) + expf(L[i][3] - mx);
    la += mx + logf(sm) - L[i][i];
  }
  for (int j = 0; j < 4; j++) {
    float mx = fmaxf(fmaxf(L[0][j], L[1][j]), fmaxf(L[2][j], L[3][j]));
    float sm = expf(L[0][j] - mx) + expf(L[1][j] - mx) + expf(L[2][j] - mx) + expf(L[3][j] - mx);
    lb += mx + logf(sm) - L[j][j];
  }
  return 0.125f * (la + lb);  // ((la/4)+(lb/4))*0.5
}

__global__ __launch_bounds__(256) void loss_k(
    const float* __restrict__ s, const float* __restrict__ f,
    const float* __restrict__ lsc, const float* __restrict__ lsf,
    float* __restrict__ out) {
  __shared__ float dots[36];
  int tid = threadIdx.x, wave = tid >> 6, lane = tid & 63;
  for (int d = wave; d < 36; d += 4) {
    const float *a, *bb;
    if (d < 16) { a = s + (d >> 2) * 1024; bb = s + (d & 3) * 1024; }
    else if (d < 32) { int e = d - 16; a = s + (e >> 2) * 1024; bb = f + (e & 3) * 1024; }
    else { a = f + (d - 32) * 1024; bb = a; }
    float p = 0.f;
    for (int k = lane; k < 1024; k += 64) p += a[k] * bb[k];
#pragma unroll
    for (int o = 32; o > 0; o >>= 1) p += __shfl_xor(p, o, 64);
    if (lane == 0) dots[d] = p;
  }
  __syncthreads();
  if (tid == 0) {
    float nS[4], nF[4];
    for (int i = 0; i < 4; i++) { nS[i] = sqrtf(dots[i * 4 + i]); nF[i] = sqrtf(dots[32 + i]); }
    float e1 = expf(lsc[0]), e2 = expf(lsf[0]);
    float L1[4][4], L2[4][4];
    for (int i = 0; i < 4; i++)
      for (int j = 0; j < 4; j++) {
        L1[i][j] = e1 * dots[i * 4 + j] / (nS[i] * nS[j]);
        L2[i][j] = e2 * dots[16 + i * 4 + j] / (nS[i] * nF[j]);
      }
    out[0] = closs_dev(L1) + closs_dev(L2);
  }
}

extern "C" void kernel_launch(void* const* d_in, const int* in_sizes, int n_in,
                              void* d_out, int out_size, void* d_ws, size_t ws_size,
                              hipStream_t stream) {
  (void)in_sizes; (void)n_in; (void)out_size; (void)ws_size;
  const float* sdata = (const float*)d_in[0];
  const int*   sidx  = (const int*)d_in[1];
  const float* emb   = (const float*)d_in[2];
  const float* fus   = (const float*)d_in[3];
  const float* ret   = (const float*)d_in[4];
  const float* ln1g  = (const float*)d_in[5];
  const float* Wq    = (const float*)d_in[6];
  const float* Wkv   = (const float*)d_in[7];
  const float* Wo    = (const float*)d_in[8];
  const float* ln2g  = (const float*)d_in[9];
  const float* Wff1  = (const float*)d_in[10];
  const float* Wff2  = (const float*)d_in[11];
  const float* normg = (const float*)d_in[12];
  const float* pWkv  = (const float*)d_in[15];
  const float* pWo   = (const float*)d_in[16];
  const float* lsc   = (const float*)d_in[17];
  const float* lsf   = (const float*)d_in[18];

  char* ws = (char*)d_ws;
  float* t   = (float*)(ws + 0L);                // 4224*1024*4  = 17,301,504
  u16* xn    = (u16*)(ws + 17301504L);           // 4224*1024*2  =  8,650,752
  char* U    = ws + 25952256L;
  u16* qkv   = (u16*)(U);                        // 4352*3072*2  = 26,738,688
  u16* vtb   = (u16*)(U + 26738688L);            // 64*64*1040*2 + pad = 8,531,968
  u16* aout  = (u16*)(U + 35270656L);            // 4224*1024*2 (attn out; dead after Wo GEMM)
  u16* ab    = (u16*)(U + 35270656L);            // 4224*2752*2 = 23,248,896 (swiglu out; reuses aout slot)
  float* par0 = (float*)(U);                     // split-K partial 0: 4224*1024*4 = 17,301,504
  float* par1 = (float*)(U + 17301504L);         // split-K partial 1 (ends 34,603,008 < ab)
  char* WT   = ws + 95698944L;                   // per-layer weights (25,296,896), reused (L3-hot)
  u16* qkvT  = (u16*)(WT);                       // 3072*1024*2
  u16* WoT   = (u16*)(WT + 6291456L);            // 1024*1024*2
  u16* f1T   = (u16*)(WT + 8388608L);            // 5504*1024*2 (column-permuted swiglu layout)
  u16* f2T   = (u16*)(WT + 19660800L);           // 1024*2752*2
  char* FIN  = ws + 120995840L;
  float* rowm   = (float*)(FIN);
  float* rinvp  = (float*)(FIN + 16640L);
  float* colsum = (float*)(FIN + 33280L);
  float* msum   = (float*)(FIN + 49664L);
  float* tmp    = (float*)(FIN + 49728L);
  float* spl    = (float*)(FIN + 66112L);
  float* fub    = (float*)(FIN + 82496L);
  const long PSTR = 4224L * 1024;

  embed_k<<<4160, 256, 0, stream>>>(sdata, sidx, emb, fus, t);

  for (int l = 0; l < 6; l++) {
    wtrans5_k<<<12352, 256, 0, stream>>>(
        Wq + (long)l * 1024 * 1024, Wkv + (long)l * 1024 * 2048,
        Wo + (long)l * 1024 * 1024, Wff1 + (long)l * 1024 * 5460,
        Wff2 + (long)l * 2730 * 1024, qkvT, WoT, f1T, f2T);

    // ln1 (layer 0: plain; else fused with previous layer's ff2 partial reduce)
    if (l == 0)
      ln_k<<<4160, 256, 0, stream>>>(t, ln1g, xn);
    else
      lnred_k<<<4160, 256, 0, stream>>>(t, par0, par1, ln1g + l * 1024, xn);

    // qkv GEMM (mode 2): writes qkv + fused V-transpose into vtb
    gemm_bt<<<33 * 24, 256, 0, stream>>>(xn, 1024, qkvT, 1024, qkv, 3072, 1024, 2, 33, 1, 0, vtb);
    attn_k<<<1088, 256, 0, stream>>>(qkv, vtb, aout);
    // Wo GEMM split-K=2 -> f32 partials at U (disjoint from aout/ab)
    gemm_bt<<<33 * 8 * 2, 256, 0, stream>>>(aout, 1024, WoT, 1024, par0, 1024, 1024, 1, 33, 2, PSTR, vtb);
    lnred_k<<<4160, 256, 0, stream>>>(t, par0, par1, ln2g + l * 1024, xn);
    // ff1 GEMM (mode 3): fused SwiGLU epilogue -> ab directly (no hb, no act_k)
    gemm_bt<<<33 * 43, 256, 0, stream>>>(xn, 1024, f1T, 1024, ab, 2752, 1024, 3, 33, 1, 0, vtb);
    // ff2 GEMM split-K=2 -> f32 partials at U (disjoint from ab)
    gemm_bt<<<33 * 8 * 2, 256, 0, stream>>>(ab, 2752, f2T, 2752, par0, 1024, 2752, 1, 33, 2, PSTR, vtb);
  }

  redrow_k<<<4160, 256, 0, stream>>>(t, par0, par1, rowm, rinvp);
  hipMemsetAsync(colsum, 0, 16448, stream);  // colsum + msum
  wcolsum_k<<<dim3(4, 52), 256, 0, stream>>>(t, rowm, rinvp, colsum, msum);
  mv1_k<<<dim3(4, 4), 256, 0, stream>>>(colsum, msum, normg, pWkv, tmp);
  mv2_k<<<dim3(4, 4), 256, 0, stream>>>(tmp, pWo, ret, spl, fub);
  loss_k<<<1, 256, 0, stream>>>(spl, fub, lsc, lsf, (float*)d_out);
}

// Round 16
// 1875.702 us; speedup vs baseline: 1.0303x; 1.0110x over previous
//
#include <hip/hip_runtime.h>

typedef unsigned short u16;
typedef unsigned long long u64;
typedef __attribute__((ext_vector_type(8))) short short8;
typedef __attribute__((ext_vector_type(4))) float f32x4;

__device__ __forceinline__ u16 f2b(float f) {
  union { float f; unsigned u; } x; x.f = f;
  unsigned r = x.u + 0x7fffu + ((x.u >> 16) & 1u);
  return (u16)(r >> 16);
}
__device__ __forceinline__ float b2f(u16 h) {
  union { unsigned u; float f; } x; x.u = ((unsigned)h) << 16;
  return x.f;
}
__device__ __forceinline__ void gld16(const void* g, void* l) {
  __builtin_amdgcn_global_load_lds(
      (__attribute__((address_space(1))) const void*)g,
      (__attribute__((address_space(3))) void*)l, 16, 0, 0);
}

// ---------------- embedding: t[b,n,:] = emb[idx]*data or fusion ----------------
__global__ __launch_bounds__(256) void embed_k(
    const float* __restrict__ data, const int* __restrict__ idx,
    const float* __restrict__ emb, const float* __restrict__ fus,
    float* __restrict__ t) {
  int row = blockIdx.x;            // 0..4159
  int b = row / 1040, n = row % 1040;
  int tid = threadIdx.x;
  const float4* src;
  float sc = 1.f;
  if (n < 1024) {
    int e = idx[b * 1024 + n];
    sc = data[b * 1024 + n];
    src = (const float4*)(emb + (long)e * 1024);
  } else {
    src = (const float4*)(fus + (long)(n - 1024) * 1024);
  }
  float4 v = src[tid];
  v.x *= sc; v.y *= sc; v.z *= sc; v.w *= sc;
  ((float4*)(t + (long)row * 1024))[tid] = v;
}

// ------------- fused 5-matrix weight transpose: f32 src[K][N] -> bf16 dst[Npad][Kpad]
//               f1T gets COLUMN-PERMUTED layout: new col nc (p=nc>>5,sub=nc&31):
//               sub<16 -> xh col p*16+sub ; sub>=16 -> gate col 2714+p*16+sub  -------------
__global__ __launch_bounds__(256) void wtrans5_k(
    const float* __restrict__ sWq, const float* __restrict__ sWkv,
    const float* __restrict__ sWo, const float* __restrict__ sW1,
    const float* __restrict__ sW2,
    u16* __restrict__ dQkvT, u16* __restrict__ dWoT,
    u16* __restrict__ dF1T, u16* __restrict__ dF2T) {
  int id = blockIdx.x;
  const float* src; u16* dst; int K, N, Kpad, nx; float sc = 1.f; int perm = 0;
  if (id < 1024)       { src = sWq;  dst = dQkvT;             K = 1024; N = 1024; Kpad = 1024; nx = 32; sc = 0.125f; }
  else if (id < 3072)  { id -= 1024; src = sWkv; dst = dQkvT + 1024 * 1024; K = 1024; N = 2048; Kpad = 1024; nx = 64; }
  else if (id < 4096)  { id -= 3072; src = sWo;  dst = dWoT;  K = 1024; N = 1024; Kpad = 1024; nx = 32; }
  else if (id < 9600)  { id -= 4096; src = sW1;  dst = dF1T;  K = 1024; N = 5504; Kpad = 1024; nx = 172; perm = 1; }
  else                 { id -= 9600; src = sW2;  dst = dF2T;  K = 2730; N = 1024; Kpad = 2752; nx = 32; }
  int n0 = (id % nx) * 32, k0 = (id / nx) * 32;
  __shared__ float tile[32][33];
  int x = threadIdx.x & 31, y = threadIdx.x >> 5;
#pragma unroll
  for (int i = 0; i < 4; i++) {
    int k = k0 + y + i * 8, n = n0 + x;
    float val = 0.f;
    if (perm) {
      int p = n >> 5, sub = n & 31;
      int o = (sub < 16) ? (p * 16 + sub) : (2714 + p * 16 + sub);
      bool ok = (sub < 16) ? (o < 2730) : (o < 5460);
      val = (k < K && ok) ? src[(long)k * 5460 + o] : 0.f;
    } else {
      val = (k < K && n < N) ? src[(long)k * N + n] * sc : 0.f;
    }
    tile[y + i * 8][x] = val;
  }
  __syncthreads();
#pragma unroll
  for (int i = 0; i < 4; i++) {
    int n = n0 + y + i * 8, k = k0 + x;
    dst[(long)n * Kpad + k] = f2b(tile[x][y + i * 8]);
  }
}

// ---------------- LayerNorm (biased var, eps 1e-5) -> bf16 ----------------
__global__ __launch_bounds__(256) void ln_k(
    const float* __restrict__ t, const float* __restrict__ g,
    u16* __restrict__ xn) {
  int row = blockIdx.x, tid = threadIdx.x;
  int wave = tid >> 6, lane = tid & 63;
  float4 v = ((const float4*)(t + (long)row * 1024))[tid];
  float s = v.x + v.y + v.z + v.w;
#pragma unroll
  for (int o = 32; o > 0; o >>= 1) s += __shfl_xor(s, o, 64);
  __shared__ float r1[4], r2[4];
  if (lane == 0) r1[wave] = s;
  __syncthreads();
  float mean = (r1[0] + r1[1] + r1[2] + r1[3]) * (1.f / 1024.f);
  float dx = v.x - mean, dy = v.y - mean, dz = v.z - mean, dw = v.w - mean;
  float q = dx * dx + dy * dy + dz * dz + dw * dw;
#pragma unroll
  for (int o = 32; o > 0; o >>= 1) q += __shfl_xor(q, o, 64);
  if (lane == 0) r2[wave] = q;
  __syncthreads();
  float var = (r2[0] + r2[1] + r2[2] + r2[3]) * (1.f / 1024.f);
  float inv = rsqrtf(var + 1e-5f);
  float4 gv = ((const float4*)g)[tid];
  u64 pack = (u64)f2b(dx * inv * gv.x)
           | ((u64)f2b(dy * inv * gv.y) << 16)
           | ((u64)f2b(dz * inv * gv.z) << 32)
           | ((u64)f2b(dw * inv * gv.w) << 48);
  *(u64*)(xn + (long)row * 1024 + tid * 4) = pack;
}

// ------- fused reduce(t += p0+p1) + LayerNorm -> bf16 -------
__global__ __launch_bounds__(256) void lnred_k(
    float* __restrict__ t, const float* __restrict__ p0, const float* __restrict__ p1,
    const float* __restrict__ g, u16* __restrict__ xn) {
  int row = blockIdx.x, tid = threadIdx.x;
  int wave = tid >> 6, lane = tid & 63;
  long base = (long)row * 1024;
  float4 v = ((const float4*)(t + base))[tid];
  float4 a = ((const float4*)(p0 + base))[tid];
  float4 bq = ((const float4*)(p1 + base))[tid];
  v.x += a.x + bq.x; v.y += a.y + bq.y; v.z += a.z + bq.z; v.w += a.w + bq.w;
  ((float4*)(t + base))[tid] = v;
  float s = v.x + v.y + v.z + v.w;
#pragma unroll
  for (int o = 32; o > 0; o >>= 1) s += __shfl_xor(s, o, 64);
  __shared__ float r1[4], r2[4];
  if (lane == 0) r1[wave] = s;
  __syncthreads();
  float mean = (r1[0] + r1[1] + r1[2] + r1[3]) * (1.f / 1024.f);
  float dx = v.x - mean, dy = v.y - mean, dz = v.z - mean, dw = v.w - mean;
  float q = dx * dx + dy * dy + dz * dz + dw * dw;
#pragma unroll
  for (int o = 32; o > 0; o >>= 1) q += __shfl_xor(q, o, 64);
  if (lane == 0) r2[wave] = q;
  __syncthreads();
  float var = (r2[0] + r2[1] + r2[2] + r2[3]) * (1.f / 1024.f);
  float inv = rsqrtf(var + 1e-5f);
  float4 gv = ((const float4*)g)[tid];
  u64 pack = (u64)f2b(dx * inv * gv.x)
           | ((u64)f2b(dy * inv * gv.y) << 16)
           | ((u64)f2b(dz * inv * gv.z) << 32)
           | ((u64)f2b(dw * inv * gv.w) << 48);
  *(u64*)(xn + base + tid * 4) = pack;
}

// ------- fused reduce(t += p0+p1) + final-LN row stats -------
__global__ __launch_bounds__(256) void redrow_k(
    float* __restrict__ t, const float* __restrict__ p0, const float* __restrict__ p1,
    float* __restrict__ rowm, float* __restrict__ rinv) {
  int row = blockIdx.x, tid = threadIdx.x;
  int wave = tid >> 6, lane = tid & 63;
  long base = (long)row * 1024;
  float4 v = ((const float4*)(t + base))[tid];
  float4 a = ((const float4*)(p0 + base))[tid];
  float4 bq = ((const float4*)(p1 + base))[tid];
  v.x += a.x + bq.x; v.y += a.y + bq.y; v.z += a.z + bq.z; v.w += a.w + bq.w;
  ((float4*)(t + base))[tid] = v;
  float s = v.x + v.y + v.z + v.w;
#pragma unroll
  for (int o = 32; o > 0; o >>= 1) s += __shfl_xor(s, o, 64);
  __shared__ float r1[4], r2[4];
  if (lane == 0) r1[wave] = s;
  __syncthreads();
  float mean = (r1[0] + r1[1] + r1[2] + r1[3]) * (1.f / 1024.f);
  float dx = v.x - mean, dy = v.y - mean, dz = v.z - mean, dw = v.w - mean;
  float q = dx * dx + dy * dy + dz * dz + dw * dw;
#pragma unroll
  for (int o = 32; o > 0; o >>= 1) q += __shfl_xor(q, o, 64);
  if (lane == 0) r2[wave] = q;
  __syncthreads();
  if (tid == 0) {
    float var = (r2[0] + r2[1] + r2[2] + r2[3]) * (1.f / 1024.f);
    rowm[row] = mean;
    rinv[row] = rsqrtf(var + 1e-5f);
  }
}

// ------- GEMM: C[M][N] = A[M][K](bf16) * Bt[N][K](bf16)^T, tile 128x128, BK=32
// mode0: bf16 store; mode1: f32 store to partial ksp; mode2: bf16 + fused V-transpose;
// mode3: fused SwiGLU epilogue (permuted f1T; tanh-gelu; writes to C[ldc=2752])
// T4 counted-vmcnt 3-deep pipeline; T2 XOR-swizzled LDS; bijective-XCD-swizzled 1D grid.
__global__ __launch_bounds__(256) void gemm_bt(
    const u16* __restrict__ A, int lda,
    const u16* __restrict__ Bt, int ldb,
    void* __restrict__ C, int ldc,
    int K, int mode, int gx, int ns, long pstride, u16* __restrict__ vt) {
  __shared__ u16 As[3][128 * 32];
  __shared__ u16 Bs[3][128 * 32];
  int tid = threadIdx.x;
  int wave = tid >> 6, lane = tid & 63;
  int col = lane & 15, grp = lane >> 4;
  // bijective XCD swizzle (m204)
  int nwg = gridDim.x;
  int id = blockIdx.x;
  int q = nwg >> 3, r = nwg & 7;
  int xcd = id & 7, off = id >> 3;
  int wgid = (xcd < r ? xcd * (q + 1) : r * (q + 1) + (xcd - r) * q) + off;
  int tiles = nwg / ns;
  int ksp = wgid / tiles;
  int rem = wgid % tiles;
  int bm = rem % gx, bn = rem / gx;
  int nst = K >> 5;
  int k0 = ((nst * ksp) / ns) << 5;
  int k1 = ((nst * (ksp + 1)) / ns) << 5;
  int sr = wave * 16 + (lane >> 2);
  // T2: pre-swizzled source k-chunk; LDS row r stores global chunk s^((r>>1)&3) at slot s.
  int sk = ((lane & 3) ^ ((lane >> 3) & 3)) * 8;
  const u16* aSrc = A + ((long)bm * 128 + sr) * lda + sk;
  const u16* bSrc = Bt + ((long)bn * 128 + sr) * ldb + sk;
  int wm = (wave >> 1) * 64, wn = (wave & 1) * 64;
  f32x4 acc[4][4] = {};

#define GSTAGE(buf, kt) do { \
    _Pragma("unroll") \
    for (int qq = 0; qq < 2; qq++) { \
      gld16(aSrc + (kt) + (long)qq * 64 * lda, &As[buf][wave * 512 + qq * 2048]); \
      gld16(bSrc + (kt) + (long)qq * 64 * ldb, &Bs[buf][wave * 512 + qq * 2048]); \
    } } while (0)

  // prologue: stage tiles 0 and 1 (4 vmem ops each)
  GSTAGE(0, k0);
  if (k0 + 32 < k1) GSTAGE(1, k0 + 32);
  int cur = 0;
  int slot = (grp ^ ((col >> 1) & 3)) * 8;     // swizzled read slot (u16)
  for (int kt = k0; kt < k1; kt += 32) {
    if (kt + 64 < k1) {
      int nb = cur + 2; if (nb >= 3) nb -= 3;
      GSTAGE(nb, kt + 64);
      asm volatile("s_waitcnt vmcnt(8)" ::: "memory");   // stage t done; t+1,t+2 in flight
    } else if (kt + 32 < k1) {
      asm volatile("s_waitcnt vmcnt(4)" ::: "memory");   // stage t done; t+1 in flight
    } else {
      asm volatile("s_waitcnt vmcnt(0)" ::: "memory");   // last tile
    }
    __builtin_amdgcn_s_barrier();                        // stage t visible to all waves
    __builtin_amdgcn_sched_barrier(0);                   // no ds_read hoisting (rule #18)
    short8 af[4], bfv[4];
#pragma unroll
    for (int m = 0; m < 4; m++)
      af[m] = *(const short8*)&As[cur][(wm + m * 16 + col) * 32 + slot];
#pragma unroll
    for (int n = 0; n < 4; n++)
      bfv[n] = *(const short8*)&Bs[cur][(wn + n * 16 + col) * 32 + slot];
    __builtin_amdgcn_s_setprio(1);
#pragma unroll
    for (int m = 0; m < 4; m++)
#pragma unroll
      for (int n = 0; n < 4; n++)
        acc[m][n] = __builtin_amdgcn_mfma_f32_16x16x32_bf16(af[m], bfv[n], acc[m][n], 0, 0, 0);
    __builtin_amdgcn_s_setprio(0);
    __builtin_amdgcn_s_barrier();                        // all reads of buf[cur] done
    __builtin_amdgcn_sched_barrier(0);                   // no gld16 sinking above barrier
    cur = (cur == 2) ? 0 : cur + 1;
  }
#undef GSTAGE
  long r0 = (long)bm * 128 + wm + grp * 4;
  int c0 = bn * 128 + wn + col;
  if (mode == 3) {
    // fused SwiGLU: fragment n even = xh block p, n odd = gate block p (same p)
    // tanh-form gelu (|err| < 3e-4 abs, far below bf16 rounding of the output)
    u16* Ab = (u16*)C;
#pragma unroll
    for (int m = 0; m < 4; m++)
#pragma unroll
      for (int np = 0; np < 2; np++) {
        int ac = ((bn * 4 + (wn >> 5) + np) << 4) + col;   // original pair index
#pragma unroll
        for (int rr = 0; rr < 4; rr++) {
          float xh = acc[m][np * 2][rr];
          float gt = acc[m][np * 2 + 1][rr];
          float rv = 0.f;
          if (ac < 2730) {
            float y = 1.5957691216f * (gt + 0.044715f * gt * gt * gt); // 2*sqrt(2/pi)*(...)
            float th = 1.f - 2.f / (__expf(y) + 1.f);                  // tanh(y/2*2)=tanh(0.79788*(...))
            rv = 0.5f * gt * (1.f + th) * xh;
          }
          Ab[(r0 + m * 16 + rr) * ldc + ac] = f2b(rv);
        }
      }
  } else if (mode != 1) {
    u16* Cb = (u16*)C;
#pragma unroll
    for (int m = 0; m < 4; m++)
#pragma unroll
      for (int n = 0; n < 4; n++)
#pragma unroll
        for (int rr = 0; rr < 4; rr++)
          Cb[(r0 + m * 16 + rr) * ldc + c0 + n * 16] = f2b(acc[m][n][rr]);
    if (mode == 2 && bn >= 16) {
      // fused V-transpose: vt[(b*16+h)*64 + d][j] = C[row=b*1040+j][2048 + h*64 + d]
#pragma unroll
      for (int m = 0; m < 4; m++) {
        long row = r0 + m * 16;                 // 4-aligned; 4 consecutive j in same b
        if (row < 4160) {
          int bidx = (int)(row / 1040);
          int j = (int)(row - (long)bidx * 1040);
#pragma unroll
          for (int n = 0; n < 4; n++) {
            int d = c0 + n * 16 - 2048;
            u64 pack = (u64)f2b(acc[m][n][0])
                     | ((u64)f2b(acc[m][n][1]) << 16)
                     | ((u64)f2b(acc[m][n][2]) << 32)
                     | ((u64)f2b(acc[m][n][3]) << 48);
            *(u64*)(vt + ((long)(bidx * 16 + (d >> 6)) * 64 + (d & 63)) * 1040 + j) = pack;
          }
        }
      }
    }
  } else {
    float* Cf = (float*)C + (long)ksp * pstride;
#pragma unroll
    for (int m = 0; m < 4; m++)
#pragma unroll
      for (int n = 0; n < 4; n++)
#pragma unroll
        for (int rr = 0; rr < 4; rr++)
          Cf[(r0 + m * 16 + rr) * ldc + c0 + n * 16] = acc[m][n][rr];
  }
}

// ------- fused flash attention: 64-row i-tiles, no-max softmax, ones-column MFMA row-sum,
//         swizzled LDS, T4 counted-vmcnt 2-buffer pipeline, XCD-chunked flat grid -------
__global__ __launch_bounds__(256) void attn_k(
    const u16* __restrict__ qkv, const u16* __restrict__ vt,
    u16* __restrict__ out) {
  int nwg = gridDim.x;
  int id = blockIdx.x;
  int q = nwg >> 3, r = nwg & 7;
  int xcd = id & 7, off = id >> 3;
  int wgid = (xcd < r ? xcd * (q + 1) : r * (q + 1) + (xcd - r) * q) + off;
  int bh = wgid / 17, it = wgid % 17;
  int b = bh >> 4, h = bh & 15;
  int tid = threadIdx.x, wave = tid >> 6, lane = tid & 63;
  int col = lane & 15, grp = lane >> 4;
  int i0 = it * 64;
  int jmax = (it == 16) ? 1040 : 1024;
  const u16* qb = qkv + (long)b * 1040 * 3072 + h * 64;
  const u16* kb = qkv + (long)b * 1040 * 3072 + 1024 + h * 64;
  const u16* vb = vt + (long)bh * 64 * 1040;
  __shared__ u16 Ks[2][64 * 64];
  __shared__ u16 Vs[2][64 * 64];
  __shared__ u16 Ps[4][16 * 64];

  int srow0 = wave * 8 + (lane >> 3);                 // row within 32-row half
  int gsw = ((lane & 7) ^ (srow0 & 7)) * 8;           // swizzled source col (u16)
#define ASTAGE(buf, j0s) do { \
    int jv = (j0s) + gsw; if (jv >= 1040) jv = 1032; \
    _Pragma("unroll") \
    for (int qq = 0; qq < 2; qq++) { \
      int rr = qq * 32 + srow0; \
      gld16(kb + (long)((j0s) + rr) * 3072 + gsw, &Ks[buf][qq * 2048 + wave * 512]); \
      gld16(vb + (long)rr * 1040 + jv, &Vs[buf][qq * 2048 + wave * 512]); \
    } } while (0)

  short8 aq[2];
  int qrow = i0 + wave * 16;
#pragma unroll
  for (int kf = 0; kf < 2; kf++)
    aq[kf] = *(const short8*)(qb + (long)(qrow + col) * 3072 + kf * 32 + grp * 8);

  short8 one8 = {};
  if (col == 0) {
#pragma unroll
    for (int i = 0; i < 8; i++) one8[i] = (short)0x3F80;   // bf16 1.0
  }

  f32x4 oa[4] = {};
  f32x4 oa1 = {};                                          // ones-column: row-sums in col 0

  ASTAGE(0, 0);           // 4 vmem ops
  int cur = 0;
  for (int j0 = 0; j0 < jmax; j0 += 64) {
    if (j0 + 64 < jmax) {
      ASTAGE(cur ^ 1, j0 + 64);                         // issue next tile (4 ops)
      asm volatile("s_waitcnt vmcnt(4)" ::: "memory");  // tile t landed; t+1 in flight
    } else {
      asm volatile("s_waitcnt vmcnt(0)" ::: "memory");  // last tile
    }
    __builtin_amdgcn_s_barrier();                       // tile t visible to all waves
    __builtin_amdgcn_sched_barrier(0);                  // no ds_read hoisting (rule #18)
    f32x4 s[4] = {};
#pragma unroll
    for (int kf = 0; kf < 2; kf++) {
      short8 bk[4];
#pragma unroll
      for (int n = 0; n < 4; n++) {
        int rk = n * 16 + col;
        bk[n] = *(const short8*)&Ks[cur][rk * 64 + ((kf * 32 + grp * 8) ^ ((rk & 7) << 3))];
      }
      __builtin_amdgcn_s_setprio(1);
#pragma unroll
      for (int n = 0; n < 4; n++)
        s[n] = __builtin_amdgcn_mfma_f32_16x16x32_bf16(aq[kf], bk[n], s[n], 0, 0, 0);
      __builtin_amdgcn_s_setprio(0);
    }
    if (j0 + 64 > jmax) {
      int lim = jmax - j0;
#pragma unroll
      for (int n = 0; n < 4; n++) {
        if (n * 16 + col >= lim) {
#pragma unroll
          for (int r2 = 0; r2 < 4; r2++) s[n][r2] = -1e30f;
        }
      }
    }
    // no-max softmax (scores structurally bounded); row-sum comes from ones-MFMA below
#pragma unroll
    for (int r2 = 0; r2 < 4; r2++) {
      int rp = grp * 4 + r2;
#pragma unroll
      for (int n = 0; n < 4; n++) {
        float p = __expf(s[n][r2]);
        Ps[wave][rp * 64 + ((n * 16 + col) ^ ((rp & 7) << 3))] = f2b(p);
      }
    }
#pragma unroll
    for (int kf = 0; kf < 2; kf++) {
      short8 ap, bv[4];
      int rm = col;
      ap = *(const short8*)&Ps[wave][rm * 64 + ((kf * 32 + grp * 8) ^ ((rm & 7) << 3))];
#pragma unroll
      for (int n = 0; n < 4; n++) {
        int rv = n * 16 + col;
        bv[n] = *(const short8*)&Vs[cur][rv * 64 + ((kf * 32 + grp * 8) ^ ((rv & 7) << 3))];
      }
      __builtin_amdgcn_s_setprio(1);
#pragma unroll
      for (int n = 0; n < 4; n++)
        oa[n] = __builtin_amdgcn_mfma_f32_16x16x32_bf16(ap, bv[n], oa[n], 0, 0, 0);
      oa1 = __builtin_amdgcn_mfma_f32_16x16x32_bf16(ap, one8, oa1, 0, 0, 0);
      __builtin_amdgcn_s_setprio(0);
    }
    __builtin_amdgcn_s_barrier();                       // all reads of buf[cur] done
    __builtin_amdgcn_sched_barrier(0);                  // no gld16 sinking above barrier
    cur ^= 1;
  }
#undef ASTAGE
  float lr[4];
#pragma unroll
  for (int r2 = 0; r2 < 4; r2++) lr[r2] = __shfl(oa1[r2], lane & 48, 64);  // broadcast col-0 row-sum
#pragma unroll
  for (int n = 0; n < 4; n++)
#pragma unroll
    for (int r2 = 0; r2 < 4; r2++) {
      int i = i0 + wave * 16 + grp * 4 + r2;
      if (i < 1040)
        out[((long)b * 1040 + i) * 1024 + h * 64 + n * 16 + col] = f2b(oa[n][r2] / lr[r2]);
    }
}

// ---------------- weighted column sum for token-mean pooling ----------------
__global__ __launch_bounds__(256) void wcolsum_k(
    const float* __restrict__ t, const float* __restrict__ rowm,
    const float* __restrict__ rinv, float* __restrict__ colsum,
    float* __restrict__ msum) {
  int b = blockIdx.x, c = blockIdx.y, tid = threadIdx.x;
  float a0 = 0, a1 = 0, a2 = 0, a3 = 0, ms = 0;
  for (int r = 0; r < 20; r++) {
    long row = (long)b * 1040 + c * 20 + r;
    float iv = rinv[row];
    float4 v = ((const float4*)(t + row * 1024))[tid];
    a0 += v.x * iv; a1 += v.y * iv; a2 += v.z * iv; a3 += v.w * iv;
    if (tid == 0) ms += rowm[row] * iv;
  }
  atomicAdd(&colsum[b * 1024 + tid * 4 + 0], a0);
  atomicAdd(&colsum[b * 1024 + tid * 4 + 1], a1);
  atomicAdd(&colsum[b * 1024 + tid * 4 + 2], a2);
  atomicAdd(&colsum[b * 1024 + tid * 4 + 3], a3);
  if (tid == 0) atomicAdd(&msum[b], ms);
}

// ---------------- pooled matvec 1: tmp = mean @ pWkv_v ----------------
__global__ __launch_bounds__(256) void mv1_k(
    const float* __restrict__ colsum, const float* __restrict__ msum,
    const float* __restrict__ g, const float* __restrict__ pWkv,
    float* __restrict__ tmp) {
  int b = blockIdx.x, n = blockIdx.y * 256 + threadIdx.x;
  float msb = msum[b];
  float acc = 0.f;
  for (int k = 0; k < 1024; k++) {
    float mk = g[k] * (colsum[b * 1024 + k] - msb);
    acc += mk * pWkv[(long)k * 2048 + 1024 + n];
  }
  tmp[b * 1024 + n] = acc * (1.f / 1040.f);
}

// ---------------- pooled matvec 2 + assemble spliced/fusion ----------------
__global__ __launch_bounds__(256) void mv2_k(
    const float* __restrict__ tmp, const float* __restrict__ pWo,
    const float* __restrict__ ret, float* __restrict__ spl,
    float* __restrict__ fub) {
  int b = blockIdx.x, n = blockIdx.y * 256 + threadIdx.x;
  float acc = 0.f;
  for (int k = 0; k < 1024; k++) acc += tmp[b * 1024 + k] * pWo[(long)k * 1024 + n];
  spl[b * 1024 + n] = ret[n] + acc;
  fub[b * 1024 + n] = ret[1024 + n] + acc;
}

// ---------------- contrastive loss ----------------
__device__ float closs_dev(const float L[4][4]) {
  float la = 0.f, lb = 0.f;
  for (int i = 0; i < 4; i++) {
    float mx = fmaxf(fmaxf(L[i][0], L[i][1]), fmaxf(L[i][2], L[i][3]));
    float sm = expf(L[i][0] - mx) + expf(L[i][1] - mx) + expf(L[i][2] - mx) + expf(L[i][3] - mx);
    la += mx + logf(sm) - L[i][i];
  }
  for (int j = 0; j < 4; j++) {
    float mx = fmaxf(fmaxf(L[0][j], L[1][j]), fmaxf(L[2][j], L[3][j]));
    float sm = expf(L[0][j] - mx) + expf(L[1][j] - mx) + expf(L[2][j] - mx) + expf(L[3][j] - mx);
    lb += mx + logf(sm) - L[j][j];
  }
  return 0.125f * (la + lb);  // ((la/4)+(lb/4))*0.5
}

__global__ __launch_bounds__(256) void loss_k(
    const float* __restrict__ s, const float* __restrict__ f,
    const float* __restrict__ lsc, const float* __restrict__ lsf,
    float* __restrict__ out) {
  __shared__ float dots[36];
  int tid = threadIdx.x, wave = tid >> 6, lane = tid & 63;
  for (int d = wave; d < 36; d += 4) {
    const float *a, *bb;
    if (d < 16) { a = s + (d >> 2) * 1024; bb = s + (d & 3) * 1024; }
    else if (d < 32) { int e = d - 16; a = s + (e >> 2) * 1024; bb = f + (e & 3) * 1024; }
    else { a = f + (d - 32) * 1024; bb = a; }
    float p = 0.f;
    for (int k = lane; k < 1024; k += 64) p += a[k] * bb[k];
#pragma unroll
    for (int o = 32; o > 0; o >>= 1) p += __shfl_xor(p, o, 64);
    if (lane == 0) dots[d] = p;
  }
  __syncthreads();
  if (tid == 0) {
    float nS[4], nF[4];
    for (int i = 0; i < 4; i++) { nS[i] = sqrtf(dots[i * 4 + i]); nF[i] = sqrtf(dots[32 + i]); }
    float e1 = expf(lsc[0]), e2 = expf(lsf[0]);
    float L1[4][4], L2[4][4];
    for (int i = 0; i < 4; i++)
      for (int j = 0; j < 4; j++) {
        L1[i][j] = e1 * dots[i * 4 + j] / (nS[i] * nS[j]);
        L2[i][j] = e2 * dots[16 + i * 4 + j] / (nS[i] * nF[j]);
      }
    out[0] = closs_dev(L1) + closs_dev(L2);
  }
}

extern "C" void kernel_launch(void* const* d_in, const int* in_sizes, int n_in,
                              void* d_out, int out_size, void* d_ws, size_t ws_size,
                              hipStream_t stream) {
  (void)in_sizes; (void)n_in; (void)out_size; (void)ws_size;
  const float* sdata = (const float*)d_in[0];
  const int*   sidx  = (const int*)d_in[1];
  const float* emb   = (const float*)d_in[2];
  const float* fus   = (const float*)d_in[3];
  const float* ret   = (const float*)d_in[4];
  const float* ln1g  = (const float*)d_in[5];
  const float* Wq    = (const float*)d_in[6];
  const float* Wkv   = (const float*)d_in[7];
  const float* Wo    = (const float*)d_in[8];
  const float* ln2g  = (const float*)d_in[9];
  const float* Wff1  = (const float*)d_in[10];
  const float* Wff2  = (const float*)d_in[11];
  const float* normg = (const float*)d_in[12];
  const float* pWkv  = (const float*)d_in[15];
  const float* pWo   = (const float*)d_in[16];
  const float* lsc   = (const float*)d_in[17];
  const float* lsf   = (const float*)d_in[18];

  char* ws = (char*)d_ws;
  float* t   = (float*)(ws + 0L);                // 4224*1024*4  = 17,301,504
  u16* xn    = (u16*)(ws + 17301504L);           // 4224*1024*2  =  8,650,752
  char* U    = ws + 25952256L;
  u16* qkv   = (u16*)(U);                        // 4352*3072*2  = 26,738,688
  u16* vtb   = (u16*)(U + 26738688L);            // 64*64*1040*2 + pad = 8,531,968
  u16* aout  = (u16*)(U + 35270656L);            // 4224*1024*2 (attn out; dead after Wo GEMM)
  u16* ab    = (u16*)(U + 35270656L);            // 4224*2752*2 = 23,248,896 (swiglu out; reuses aout slot)
  float* par0 = (float*)(U);                     // split-K partial 0: 4224*1024*4 = 17,301,504
  float* par1 = (float*)(U + 17301504L);         // split-K partial 1 (ends 34,603,008 < ab)
  char* WT   = ws + 95698944L;                   // per-layer weights (25,296,896), reused (L3-hot)
  u16* qkvT  = (u16*)(WT);                       // 3072*1024*2
  u16* WoT   = (u16*)(WT + 6291456L);            // 1024*1024*2
  u16* f1T   = (u16*)(WT + 8388608L);            // 5504*1024*2 (column-permuted swiglu layout)
  u16* f2T   = (u16*)(WT + 19660800L);           // 1024*2752*2
  char* FIN  = ws + 120995840L;
  float* rowm   = (float*)(FIN);
  float* rinvp  = (float*)(FIN + 16640L);
  float* colsum = (float*)(FIN + 33280L);
  float* msum   = (float*)(FIN + 49664L);
  float* tmp    = (float*)(FIN + 49728L);
  float* spl    = (float*)(FIN + 66112L);
  float* fub    = (float*)(FIN + 82496L);
  const long PSTR = 4224L * 1024;

  embed_k<<<4160, 256, 0, stream>>>(sdata, sidx, emb, fus, t);

  for (int l = 0; l < 6; l++) {
    wtrans5_k<<<12352, 256, 0, stream>>>(
        Wq + (long)l * 1024 * 1024, Wkv + (long)l * 1024 * 2048,
        Wo + (long)l * 1024 * 1024, Wff1 + (long)l * 1024 * 5460,
        Wff2 + (long)l * 2730 * 1024, qkvT, WoT, f1T, f2T);

    // ln1 (layer 0: plain; else fused with previous layer's ff2 partial reduce)
    if (l == 0)
      ln_k<<<4160, 256, 0, stream>>>(t, ln1g, xn);
    else
      lnred_k<<<4160, 256, 0, stream>>>(t, par0, par1, ln1g + l * 1024, xn);

    // qkv GEMM (mode 2): writes qkv + fused V-transpose into vtb
    gemm_bt<<<33 * 24, 256, 0, stream>>>(xn, 1024, qkvT, 1024, qkv, 3072, 1024, 2, 33, 1, 0, vtb);
    attn_k<<<1088, 256, 0, stream>>>(qkv, vtb, aout);
    // Wo GEMM split-K=2 -> f32 partials at U (disjoint from aout/ab)
    gemm_bt<<<33 * 8 * 2, 256, 0, stream>>>(aout, 1024, WoT, 1024, par0, 1024, 1024, 1, 33, 2, PSTR, vtb);
    lnred_k<<<4160, 256, 0, stream>>>(t, par0, par1, ln2g + l * 1024, xn);
    // ff1 GEMM (mode 3): fused SwiGLU epilogue -> ab directly (no hb, no act_k)
    gemm_bt<<<33 * 43, 256, 0, stream>>>(xn, 1024, f1T, 1024, ab, 2752, 1024, 3, 33, 1, 0, vtb);
    // ff2 GEMM split-K=2 -> f32 partials at U (disjoint from ab)
    gemm_bt<<<33 * 8 * 2, 256, 0, stream>>>(ab, 2752, f2T, 2752, par0, 1024, 2752, 1, 33, 2, PSTR, vtb);
  }

  redrow_k<<<4160, 256, 0, stream>>>(t, par0, par1, rowm, rinvp);
  hipMemsetAsync(colsum, 0, 16448, stream);  // colsum + msum
  wcolsum_k<<<dim3(4, 52), 256, 0, stream>>>(t, rowm, rinvp, colsum, msum);
  mv1_k<<<dim3(4, 4), 256, 0, stream>>>(colsum, msum, normg, pWkv, tmp);
  mv2_k<<<dim3(4, 4), 256, 0, stream>>>(tmp, pWo, ret, spl, fub);
  loss_k<<<1, 256, 0, stream>>>(spl, fub, lsc, lsf, (float*)d_out);
}

// Round 17
// 1762.964 us; speedup vs baseline: 1.0962x; 1.0639x over previous
//
#include <hip/hip_runtime.h>

typedef unsigned short u16;
typedef unsigned long long u64;
typedef __attribute__((ext_vector_type(8))) short short8;
typedef __attribute__((ext_vector_type(4))) float f32x4;

__device__ __forceinline__ u16 f2b(float f) {
  union { float f; unsigned u; } x; x.f = f;
  unsigned r = x.u + 0x7fffu + ((x.u >> 16) & 1u);
  return (u16)(r >> 16);
}
__device__ __forceinline__ float b2f(u16 h) {
  union { unsigned u; float f; } x; x.u = ((unsigned)h) << 16;
  return x.f;
}
__device__ __forceinline__ void gld16(const void* g, void* l) {
  __builtin_amdgcn_global_load_lds(
      (__attribute__((address_space(1))) const void*)g,
      (__attribute__((address_space(3))) void*)l, 16, 0, 0);
}

// ---------------- embedding: t[b,n,:] = emb[idx]*data or fusion ----------------
__global__ __launch_bounds__(256) void embed_k(
    const float* __restrict__ data, const int* __restrict__ idx,
    const float* __restrict__ emb, const float* __restrict__ fus,
    float* __restrict__ t) {
  int row = blockIdx.x;            // 0..4159
  int b = row / 1040, n = row % 1040;
  int tid = threadIdx.x;
  const float4* src;
  float sc = 1.f;
  if (n < 1024) {
    int e = idx[b * 1024 + n];
    sc = data[b * 1024 + n];
    src = (const float4*)(emb + (long)e * 1024);
  } else {
    src = (const float4*)(fus + (long)(n - 1024) * 1024);
  }
  float4 v = src[tid];
  v.x *= sc; v.y *= sc; v.z *= sc; v.w *= sc;
  ((float4*)(t + (long)row * 1024))[tid] = v;
}

// ------------- fused 5-matrix weight transpose: f32 src[K][N] -> bf16 dst[Npad][Kpad]
//               f1T gets COLUMN-PERMUTED layout: new col nc (p=nc>>5,sub=nc&31):
//               sub<16 -> xh col p*16+sub ; sub>=16 -> gate col 2714+p*16+sub  -------------
__global__ __launch_bounds__(256) void wtrans5_k(
    const float* __restrict__ sWq, const float* __restrict__ sWkv,
    const float* __restrict__ sWo, const float* __restrict__ sW1,
    const float* __restrict__ sW2,
    u16* __restrict__ dQkvT, u16* __restrict__ dWoT,
    u16* __restrict__ dF1T, u16* __restrict__ dF2T) {
  int id = blockIdx.x;
  const float* src; u16* dst; int K, N, Kpad, nx; float sc = 1.f; int perm = 0;
  if (id < 1024)       { src = sWq;  dst = dQkvT;             K = 1024; N = 1024; Kpad = 1024; nx = 32; sc = 0.125f; }
  else if (id < 3072)  { id -= 1024; src = sWkv; dst = dQkvT + 1024 * 1024; K = 1024; N = 2048; Kpad = 1024; nx = 64; }
  else if (id < 4096)  { id -= 3072; src = sWo;  dst = dWoT;  K = 1024; N = 1024; Kpad = 1024; nx = 32; }
  else if (id < 9600)  { id -= 4096; src = sW1;  dst = dF1T;  K = 1024; N = 5504; Kpad = 1024; nx = 172; perm = 1; }
  else                 { id -= 9600; src = sW2;  dst = dF2T;  K = 2730; N = 1024; Kpad = 2752; nx = 32; }
  int n0 = (id % nx) * 32, k0 = (id / nx) * 32;
  __shared__ float tile[32][33];
  int x = threadIdx.x & 31, y = threadIdx.x >> 5;
#pragma unroll
  for (int i = 0; i < 4; i++) {
    int k = k0 + y + i * 8, n = n0 + x;
    float val = 0.f;
    if (perm) {
      int p = n >> 5, sub = n & 31;
      int o = (sub < 16) ? (p * 16 + sub) : (2714 + p * 16 + sub);
      bool ok = (sub < 16) ? (o < 2730) : (o < 5460);
      val = (k < K && ok) ? src[(long)k * 5460 + o] : 0.f;
    } else {
      val = (k < K && n < N) ? src[(long)k * N + n] * sc : 0.f;
    }
    tile[y + i * 8][x] = val;
  }
  __syncthreads();
#pragma unroll
  for (int i = 0; i < 4; i++) {
    int n = n0 + y + i * 8, k = k0 + x;
    dst[(long)n * Kpad + k] = f2b(tile[x][y + i * 8]);
  }
}

// ---------------- LayerNorm (biased var, eps 1e-5) -> bf16 ----------------
__global__ __launch_bounds__(256) void ln_k(
    const float* __restrict__ t, const float* __restrict__ g,
    u16* __restrict__ xn) {
  int row = blockIdx.x, tid = threadIdx.x;
  int wave = tid >> 6, lane = tid & 63;
  float4 v = ((const float4*)(t + (long)row * 1024))[tid];
  float s = v.x + v.y + v.z + v.w;
#pragma unroll
  for (int o = 32; o > 0; o >>= 1) s += __shfl_xor(s, o, 64);
  __shared__ float r1[4], r2[4];
  if (lane == 0) r1[wave] = s;
  __syncthreads();
  float mean = (r1[0] + r1[1] + r1[2] + r1[3]) * (1.f / 1024.f);
  float dx = v.x - mean, dy = v.y - mean, dz = v.z - mean, dw = v.w - mean;
  float q = dx * dx + dy * dy + dz * dz + dw * dw;
#pragma unroll
  for (int o = 32; o > 0; o >>= 1) q += __shfl_xor(q, o, 64);
  if (lane == 0) r2[wave] = q;
  __syncthreads();
  float var = (r2[0] + r2[1] + r2[2] + r2[3]) * (1.f / 1024.f);
  float inv = rsqrtf(var + 1e-5f);
  float4 gv = ((const float4*)g)[tid];
  u64 pack = (u64)f2b(dx * inv * gv.x)
           | ((u64)f2b(dy * inv * gv.y) << 16)
           | ((u64)f2b(dz * inv * gv.z) << 32)
           | ((u64)f2b(dw * inv * gv.w) << 48);
  *(u64*)(xn + (long)row * 1024 + tid * 4) = pack;
}

// ------- fused reduce(t += p0+p1) + LayerNorm -> bf16 -------
__global__ __launch_bounds__(256) void lnred_k(
    float* __restrict__ t, const float* __restrict__ p0, const float* __restrict__ p1,
    const float* __restrict__ g, u16* __restrict__ xn) {
  int row = blockIdx.x, tid = threadIdx.x;
  int wave = tid >> 6, lane = tid & 63;
  long base = (long)row * 1024;
  float4 v = ((const float4*)(t + base))[tid];
  float4 a = ((const float4*)(p0 + base))[tid];
  float4 bq = ((const float4*)(p1 + base))[tid];
  v.x += a.x + bq.x; v.y += a.y + bq.y; v.z += a.z + bq.z; v.w += a.w + bq.w;
  ((float4*)(t + base))[tid] = v;
  float s = v.x + v.y + v.z + v.w;
#pragma unroll
  for (int o = 32; o > 0; o >>= 1) s += __shfl_xor(s, o, 64);
  __shared__ float r1[4], r2[4];
  if (lane == 0) r1[wave] = s;
  __syncthreads();
  float mean = (r1[0] + r1[1] + r1[2] + r1[3]) * (1.f / 1024.f);
  float dx = v.x - mean, dy = v.y - mean, dz = v.z - mean, dw = v.w - mean;
  float q = dx * dx + dy * dy + dz * dz + dw * dw;
#pragma unroll
  for (int o = 32; o > 0; o >>= 1) q += __shfl_xor(q, o, 64);
  if (lane == 0) r2[wave] = q;
  __syncthreads();
  float var = (r2[0] + r2[1] + r2[2] + r2[3]) * (1.f / 1024.f);
  float inv = rsqrtf(var + 1e-5f);
  float4 gv = ((const float4*)g)[tid];
  u64 pack = (u64)f2b(dx * inv * gv.x)
           | ((u64)f2b(dy * inv * gv.y) << 16)
           | ((u64)f2b(dz * inv * gv.z) << 32)
           | ((u64)f2b(dw * inv * gv.w) << 48);
  *(u64*)(xn + base + tid * 4) = pack;
}

// ------- fused reduce(t += p0+p1) + final-LN row stats -------
__global__ __launch_bounds__(256) void redrow_k(
    float* __restrict__ t, const float* __restrict__ p0, const float* __restrict__ p1,
    float* __restrict__ rowm, float* __restrict__ rinv) {
  int row = blockIdx.x, tid = threadIdx.x;
  int wave = tid >> 6, lane = tid & 63;
  long base = (long)row * 1024;
  float4 v = ((const float4*)(t + base))[tid];
  float4 a = ((const float4*)(p0 + base))[tid];
  float4 bq = ((const float4*)(p1 + base))[tid];
  v.x += a.x + bq.x; v.y += a.y + bq.y; v.z += a.z + bq.z; v.w += a.w + bq.w;
  ((float4*)(t + base))[tid] = v;
  float s = v.x + v.y + v.z + v.w;
#pragma unroll
  for (int o = 32; o > 0; o >>= 1) s += __shfl_xor(s, o, 64);
  __shared__ float r1[4], r2[4];
  if (lane == 0) r1[wave] = s;
  __syncthreads();
  float mean = (r1[0] + r1[1] + r1[2] + r1[3]) * (1.f / 1024.f);
  float dx = v.x - mean, dy = v.y - mean, dz = v.z - mean, dw = v.w - mean;
  float q = dx * dx + dy * dy + dz * dz + dw * dw;
#pragma unroll
  for (int o = 32; o > 0; o >>= 1) q += __shfl_xor(q, o, 64);
  if (lane == 0) r2[wave] = q;
  __syncthreads();
  if (tid == 0) {
    float var = (r2[0] + r2[1] + r2[2] + r2[3]) * (1.f / 1024.f);
    rowm[row] = mean;
    rinv[row] = rsqrtf(var + 1e-5f);
  }
}

// ------- GEMM: C[M][N] = A[M][K](bf16) * Bt[N][K](bf16)^T, tile 128x128, BK=32
// mode0: bf16 store; mode1: f32 store to partial ksp; mode2: bf16 + fused V-transpose;
// mode3: fused SwiGLU epilogue (permuted f1T; tanh-gelu; writes to C[ldc=2752])
// T4 counted-vmcnt 3-deep pipeline; T2 XOR-swizzled LDS; bijective-XCD-swizzled 1D grid.
__global__ __launch_bounds__(256) void gemm_bt(
    const u16* __restrict__ A, int lda,
    const u16* __restrict__ Bt, int ldb,
    void* __restrict__ C, int ldc,
    int K, int mode, int gx, int ns, long pstride, u16* __restrict__ vt) {
  __shared__ u16 As[3][128 * 32];
  __shared__ u16 Bs[3][128 * 32];
  int tid = threadIdx.x;
  int wave = tid >> 6, lane = tid & 63;
  int col = lane & 15, grp = lane >> 4;
  // bijective XCD swizzle (m204)
  int nwg = gridDim.x;
  int id = blockIdx.x;
  int q = nwg >> 3, r = nwg & 7;
  int xcd = id & 7, off = id >> 3;
  int wgid = (xcd < r ? xcd * (q + 1) : r * (q + 1) + (xcd - r) * q) + off;
  int tiles = nwg / ns;
  int ksp = wgid / tiles;
  int rem = wgid % tiles;
  int bm = rem % gx, bn = rem / gx;
  int nst = K >> 5;
  int k0 = ((nst * ksp) / ns) << 5;
  int k1 = ((nst * (ksp + 1)) / ns) << 5;
  int sr = wave * 16 + (lane >> 2);
  // T2: pre-swizzled source k-chunk; LDS row r stores global chunk s^((r>>1)&3) at slot s.
  int sk = ((lane & 3) ^ ((lane >> 3) & 3)) * 8;
  const u16* aSrc = A + ((long)bm * 128 + sr) * lda + sk;
  const u16* bSrc = Bt + ((long)bn * 128 + sr) * ldb + sk;
  int wm = (wave >> 1) * 64, wn = (wave & 1) * 64;
  f32x4 acc[4][4] = {};

#define GSTAGE(buf, kt) do { \
    _Pragma("unroll") \
    for (int qq = 0; qq < 2; qq++) { \
      gld16(aSrc + (kt) + (long)qq * 64 * lda, &As[buf][wave * 512 + qq * 2048]); \
      gld16(bSrc + (kt) + (long)qq * 64 * ldb, &Bs[buf][wave * 512 + qq * 2048]); \
    } } while (0)

  // prologue: stage tiles 0 and 1 (4 vmem ops each)
  GSTAGE(0, k0);
  if (k0 + 32 < k1) GSTAGE(1, k0 + 32);
  int cur = 0;
  int slot = (grp ^ ((col >> 1) & 3)) * 8;     // swizzled read slot (u16)
  for (int kt = k0; kt < k1; kt += 32) {
    if (kt + 64 < k1) {
      int nb = cur + 2; if (nb >= 3) nb -= 3;
      GSTAGE(nb, kt + 64);
      asm volatile("s_waitcnt vmcnt(8)" ::: "memory");   // stage t done; t+1,t+2 in flight
    } else if (kt + 32 < k1) {
      asm volatile("s_waitcnt vmcnt(4)" ::: "memory");   // stage t done; t+1 in flight
    } else {
      asm volatile("s_waitcnt vmcnt(0)" ::: "memory");   // last tile
    }
    __builtin_amdgcn_s_barrier();                        // stage t visible to all waves
    __builtin_amdgcn_sched_barrier(0);                   // no ds_read hoisting (rule #18)
    short8 af[4], bfv[4];
#pragma unroll
    for (int m = 0; m < 4; m++)
      af[m] = *(const short8*)&As[cur][(wm + m * 16 + col) * 32 + slot];
#pragma unroll
    for (int n = 0; n < 4; n++)
      bfv[n] = *(const short8*)&Bs[cur][(wn + n * 16 + col) * 32 + slot];
    __builtin_amdgcn_s_setprio(1);
#pragma unroll
    for (int m = 0; m < 4; m++)
#pragma unroll
      for (int n = 0; n < 4; n++)
        acc[m][n] = __builtin_amdgcn_mfma_f32_16x16x32_bf16(af[m], bfv[n], acc[m][n], 0, 0, 0);
    __builtin_amdgcn_s_setprio(0);
    __builtin_amdgcn_s_barrier();                        // all reads of buf[cur] done
    __builtin_amdgcn_sched_barrier(0);                   // no gld16 sinking above barrier
    cur = (cur == 2) ? 0 : cur + 1;
  }
#undef GSTAGE
  long r0 = (long)bm * 128 + wm + grp * 4;
  int c0 = bn * 128 + wn + col;
  if (mode == 3) {
    // fused SwiGLU: fragment n even = xh block p, n odd = gate block p (same p)
    // tanh-form gelu (|err| < 3e-4 abs, far below bf16 rounding of the output)
    u16* Ab = (u16*)C;
#pragma unroll
    for (int m = 0; m < 4; m++)
#pragma unroll
      for (int np = 0; np < 2; np++) {
        int ac = ((bn * 4 + (wn >> 5) + np) << 4) + col;   // original pair index
#pragma unroll
        for (int rr = 0; rr < 4; rr++) {
          float xh = acc[m][np * 2][rr];
          float gt = acc[m][np * 2 + 1][rr];
          float rv = 0.f;
          if (ac < 2730) {
            float y = 1.5957691216f * (gt + 0.044715f * gt * gt * gt); // 2*sqrt(2/pi)*(...)
            float th = 1.f - 2.f / (__expf(y) + 1.f);
            rv = 0.5f * gt * (1.f + th) * xh;
          }
          Ab[(r0 + m * 16 + rr) * ldc + ac] = f2b(rv);
        }
      }
  } else if (mode != 1) {
    u16* Cb = (u16*)C;
#pragma unroll
    for (int m = 0; m < 4; m++)
#pragma unroll
      for (int n = 0; n < 4; n++)
#pragma unroll
        for (int rr = 0; rr < 4; rr++)
          Cb[(r0 + m * 16 + rr) * ldc + c0 + n * 16] = f2b(acc[m][n][rr]);
    if (mode == 2 && bn >= 16) {
      // fused V-transpose: vt[(b*16+h)*64 + d][j] = C[row=b*1040+j][2048 + h*64 + d]
#pragma unroll
      for (int m = 0; m < 4; m++) {
        long row = r0 + m * 16;                 // 4-aligned; 4 consecutive j in same b
        if (row < 4160) {
          int bidx = (int)(row / 1040);
          int j = (int)(row - (long)bidx * 1040);
#pragma unroll
          for (int n = 0; n < 4; n++) {
            int d = c0 + n * 16 - 2048;
            u64 pack = (u64)f2b(acc[m][n][0])
                     | ((u64)f2b(acc[m][n][1]) << 16)
                     | ((u64)f2b(acc[m][n][2]) << 32)
                     | ((u64)f2b(acc[m][n][3]) << 48);
            *(u64*)(vt + ((long)(bidx * 16 + (d >> 6)) * 64 + (d & 63)) * 1040 + j) = pack;
          }
        }
      }
    }
  } else {
    float* Cf = (float*)C + (long)ksp * pstride;
#pragma unroll
    for (int m = 0; m < 4; m++)
#pragma unroll
      for (int n = 0; n < 4; n++)
#pragma unroll
        for (int rr = 0; rr < 4; rr++)
          Cf[(r0 + m * 16 + rr) * ldc + c0 + n * 16] = acc[m][n][rr];
  }
}

// ------- fused flash attention: 64-row i-tiles, no-max softmax, ones-column MFMA row-sum,
//         swizzled LDS, T4 counted-vmcnt 2-buffer pipeline, XCD-chunked flat grid -------
__global__ __launch_bounds__(256) void attn_k(
    const u16* __restrict__ qkv, const u16* __restrict__ vt,
    u16* __restrict__ out) {
  int nwg = gridDim.x;
  int id = blockIdx.x;
  int q = nwg >> 3, r = nwg & 7;
  int xcd = id & 7, off = id >> 3;
  int wgid = (xcd < r ? xcd * (q + 1) : r * (q + 1) + (xcd - r) * q) + off;
  int bh = wgid / 17, it = wgid % 17;
  int b = bh >> 4, h = bh & 15;
  int tid = threadIdx.x, wave = tid >> 6, lane = tid & 63;
  int col = lane & 15, grp = lane >> 4;
  int i0 = it * 64;
  int jmax = (it == 16) ? 1040 : 1024;
  const u16* qb = qkv + (long)b * 1040 * 3072 + h * 64;
  const u16* kb = qkv + (long)b * 1040 * 3072 + 1024 + h * 64;
  const u16* vb = vt + (long)bh * 64 * 1040;
  __shared__ u16 Ks[2][64 * 64];
  __shared__ u16 Vs[2][64 * 64];
  __shared__ u16 Ps[4][16 * 64];

  int srow0 = wave * 8 + (lane >> 3);                 // row within 32-row half
  int gsw = ((lane & 7) ^ (srow0 & 7)) * 8;           // swizzled source col (u16)
#define ASTAGE(buf, j0s) do { \
    int jv = (j0s) + gsw; if (jv >= 1040) jv = 1032; \
    _Pragma("unroll") \
    for (int qq = 0; qq < 2; qq++) { \
      int rr = qq * 32 + srow0; \
      gld16(kb + (long)((j0s) + rr) * 3072 + gsw, &Ks[buf][qq * 2048 + wave * 512]); \
      gld16(vb + (long)rr * 1040 + jv, &Vs[buf][qq * 2048 + wave * 512]); \
    } } while (0)

  short8 aq[2];
  int qrow = i0 + wave * 16;
#pragma unroll
  for (int kf = 0; kf < 2; kf++)
    aq[kf] = *(const short8*)(qb + (long)(qrow + col) * 3072 + kf * 32 + grp * 8);

  short8 one8 = {};
  if (col == 0) {
#pragma unroll
    for (int i = 0; i < 8; i++) one8[i] = (short)0x3F80;   // bf16 1.0
  }

  f32x4 oa[4] = {};
  f32x4 oa1 = {};                                          // ones-column: row-sums in col 0

  ASTAGE(0, 0);           // 4 vmem ops
  int cur = 0;
  for (int j0 = 0; j0 < jmax; j0 += 64) {
    if (j0 + 64 < jmax) {
      ASTAGE(cur ^ 1, j0 + 64);                         // issue next tile (4 ops)
      asm volatile("s_waitcnt vmcnt(4)" ::: "memory");  // tile t landed; t+1 in flight
    } else {
      asm volatile("s_waitcnt vmcnt(0)" ::: "memory");  // last tile
    }
    __builtin_amdgcn_s_barrier();                       // tile t visible to all waves
    __builtin_amdgcn_sched_barrier(0);                  // no ds_read hoisting (rule #18)
    f32x4 s[4] = {};
#pragma unroll
    for (int kf = 0; kf < 2; kf++) {
      short8 bk[4];
#pragma unroll
      for (int n = 0; n < 4; n++) {
        int rk = n * 16 + col;
        bk[n] = *(const short8*)&Ks[cur][rk * 64 + ((kf * 32 + grp * 8) ^ ((rk & 7) << 3))];
      }
      __builtin_amdgcn_s_setprio(1);
#pragma unroll
      for (int n = 0; n < 4; n++)
        s[n] = __builtin_amdgcn_mfma_f32_16x16x32_bf16(aq[kf], bk[n], s[n], 0, 0, 0);
      __builtin_amdgcn_s_setprio(0);
    }
    if (j0 + 64 > jmax) {
      int lim = jmax - j0;
#pragma unroll
      for (int n = 0; n < 4; n++) {
        if (n * 16 + col >= lim) {
#pragma unroll
          for (int r2 = 0; r2 < 4; r2++) s[n][r2] = -1e30f;
        }
      }
    }
    // no-max softmax (scores structurally bounded); row-sum comes from ones-MFMA below
#pragma unroll
    for (int r2 = 0; r2 < 4; r2++) {
      int rp = grp * 4 + r2;
#pragma unroll
      for (int n = 0; n < 4; n++) {
        float p = __expf(s[n][r2]);
        Ps[wave][rp * 64 + ((n * 16 + col) ^ ((rp & 7) << 3))] = f2b(p);
      }
    }
#pragma unroll
    for (int kf = 0; kf < 2; kf++) {
      short8 ap, bv[4];
      int rm = col;
      ap = *(const short8*)&Ps[wave][rm * 64 + ((kf * 32 + grp * 8) ^ ((rm & 7) << 3))];
#pragma unroll
      for (int n = 0; n < 4; n++) {
        int rv = n * 16 + col;
        bv[n] = *(const short8*)&Vs[cur][rv * 64 + ((kf * 32 + grp * 8) ^ ((rv & 7) << 3))];
      }
      __builtin_amdgcn_s_setprio(1);
#pragma unroll
      for (int n = 0; n < 4; n++)
        oa[n] = __builtin_amdgcn_mfma_f32_16x16x32_bf16(ap, bv[n], oa[n], 0, 0, 0);
      oa1 = __builtin_amdgcn_mfma_f32_16x16x32_bf16(ap, one8, oa1, 0, 0, 0);
      __builtin_amdgcn_s_setprio(0);
    }
    __builtin_amdgcn_s_barrier();                       // all reads of buf[cur] done
    __builtin_amdgcn_sched_barrier(0);                  // no gld16 sinking above barrier
    cur ^= 1;
  }
#undef ASTAGE
  float lr[4];
#pragma unroll
  for (int r2 = 0; r2 < 4; r2++) lr[r2] = __shfl(oa1[r2], lane & 48, 64);  // broadcast col-0 row-sum
#pragma unroll
  for (int n = 0; n < 4; n++)
#pragma unroll
    for (int r2 = 0; r2 < 4; r2++) {
      int i = i0 + wave * 16 + grp * 4 + r2;
      if (i < 1040)
        out[((long)b * 1040 + i) * 1024 + h * 64 + n * 16 + col] = f2b(oa[n][r2] / lr[r2]);
    }
}

// ---------------- weighted column sum for token-mean pooling ----------------
__global__ __launch_bounds__(256) void wcolsum_k(
    const float* __restrict__ t, const float* __restrict__ rowm,
    const float* __restrict__ rinv, float* __restrict__ colsum,
    float* __restrict__ msum) {
  int b = blockIdx.x, c = blockIdx.y, tid = threadIdx.x;
  float a0 = 0, a1 = 0, a2 = 0, a3 = 0, ms = 0;
  for (int r = 0; r < 20; r++) {
    long row = (long)b * 1040 + c * 20 + r;
    float iv = rinv[row];
    float4 v = ((const float4*)(t + row * 1024))[tid];
    a0 += v.x * iv; a1 += v.y * iv; a2 += v.z * iv; a3 += v.w * iv;
    if (tid == 0) ms += rowm[row] * iv;
  }
  atomicAdd(&colsum[b * 1024 + tid * 4 + 0], a0);
  atomicAdd(&colsum[b * 1024 + tid * 4 + 1], a1);
  atomicAdd(&colsum[b * 1024 + tid * 4 + 2], a2);
  atomicAdd(&colsum[b * 1024 + tid * 4 + 3], a3);
  if (tid == 0) atomicAdd(&msum[b], ms);
}

// ------- pooled matvec 1 (parallel): tmp[b][n] = (1/1040) * sum_k mk[b][k]*pWkv[k][1024+n]
//         grid (4,16); 4 waves split K into 256-chunks; LDS reduce -------
__global__ __launch_bounds__(256) void mv1_k(
    const float* __restrict__ colsum, const float* __restrict__ msum,
    const float* __restrict__ g, const float* __restrict__ pWkv,
    float* __restrict__ tmp) {
  int b = blockIdx.x, n0 = blockIdx.y * 64;
  int tid = threadIdx.x;
  int n = tid & 63, s = tid >> 6;
  float msb = msum[b];
  float acc = 0.f;
  int ks = s * 256;
  for (int k = ks; k < ks + 256; k++) {
    float mk = g[k] * (colsum[b * 1024 + k] - msb);
    acc += mk * pWkv[(long)k * 2048 + 1024 + n0 + n];
  }
  __shared__ float red[4][64];
  red[s][n] = acc;
  __syncthreads();
  if (s == 0)
    tmp[b * 1024 + n0 + n] = (red[0][n] + red[1][n] + red[2][n] + red[3][n]) * (1.f / 1040.f);
}

// ------- pooled matvec 2 (parallel) + assemble spliced/fusion -------
__global__ __launch_bounds__(256) void mv2_k(
    const float* __restrict__ tmp, const float* __restrict__ pWo,
    const float* __restrict__ ret, float* __restrict__ spl,
    float* __restrict__ fub) {
  int b = blockIdx.x, n0 = blockIdx.y * 64;
  int tid = threadIdx.x;
  int n = tid & 63, s = tid >> 6;
  float acc = 0.f;
  int ks = s * 256;
  for (int k = ks; k < ks + 256; k++)
    acc += tmp[b * 1024 + k] * pWo[(long)k * 1024 + n0 + n];
  __shared__ float red[4][64];
  red[s][n] = acc;
  __syncthreads();
  if (s == 0) {
    float v = red[0][n] + red[1][n] + red[2][n] + red[3][n];
    spl[b * 1024 + n0 + n] = ret[n0 + n] + v;
    fub[b * 1024 + n0 + n] = ret[1024 + n0 + n] + v;
  }
}

// ---------------- contrastive loss: parallel dots (36 blocks) + tiny finisher ----------------
__global__ __launch_bounds__(256) void dots_k(
    const float* __restrict__ s, const float* __restrict__ f,
    float* __restrict__ dots) {
  int d = blockIdx.x, tid = threadIdx.x;
  int wave = tid >> 6, lane = tid & 63;
  const float *a, *bb;
  if (d < 16) { a = s + (d >> 2) * 1024; bb = s + (d & 3) * 1024; }
  else if (d < 32) { int e = d - 16; a = s + (e >> 2) * 1024; bb = f + (e & 3) * 1024; }
  else { a = f + (d - 32) * 1024; bb = a; }
  float4 va = ((const float4*)a)[tid];
  float4 vb = ((const float4*)bb)[tid];
  float p = va.x * vb.x + va.y * vb.y + va.z * vb.z + va.w * vb.w;
#pragma unroll
  for (int o = 32; o > 0; o >>= 1) p += __shfl_xor(p, o, 64);
  __shared__ float r[4];
  if (lane == 0) r[wave] = p;
  __syncthreads();
  if (tid == 0) dots[d] = r[0] + r[1] + r[2] + r[3];
}

__device__ float closs_dev(const float L[4][4]) {
  float la = 0.f, lb = 0.f;
  for (int i = 0; i < 4; i++) {
    float mx = fmaxf(fmaxf(L[i][0], L[i][1]), fmaxf(L[i][2], L[i][3]));
    float sm = expf(L[i][0] - mx) + expf(L[i][1] - mx) + expf(L[i][2] - mx) + expf(L[i][3] - mx);
    la += mx + logf(sm) - L[i][i];
  }
  for (int j = 0; j < 4; j++) {
    float mx = fmaxf(fmaxf(L[0][j], L[1][j]), fmaxf(L[2][j], L[3][j]));
    float sm = expf(L[0][j] - mx) + expf(L[1][j] - mx) + expf(L[2][j] - mx) + expf(L[3][j] - mx);
    lb += mx + logf(sm) - L[j][j];
  }
  return 0.125f * (la + lb);  // ((la/4)+(lb/4))*0.5
}

__global__ __launch_bounds__(64) void loss_fin_k(
    const float* __restrict__ dots,
    const float* __restrict__ lsc, const float* __restrict__ lsf,
    float* __restrict__ out) {
  if (threadIdx.x == 0) {
    float nS[4], nF[4];
    for (int i = 0; i < 4; i++) { nS[i] = sqrtf(dots[i * 4 + i]); nF[i] = sqrtf(dots[32 + i]); }
    float e1 = expf(lsc[0]), e2 = expf(lsf[0]);
    float L1[4][4], L2[4][4];
    for (int i = 0; i < 4; i++)
      for (int j = 0; j < 4; j++) {
        L1[i][j] = e1 * dots[i * 4 + j] / (nS[i] * nS[j]);
        L2[i][j] = e2 * dots[16 + i * 4 + j] / (nS[i] * nF[j]);
      }
    out[0] = closs_dev(L1) + closs_dev(L2);
  }
}

extern "C" void kernel_launch(void* const* d_in, const int* in_sizes, int n_in,
                              void* d_out, int out_size, void* d_ws, size_t ws_size,
                              hipStream_t stream) {
  (void)in_sizes; (void)n_in; (void)out_size; (void)ws_size;
  const float* sdata = (const float*)d_in[0];
  const int*   sidx  = (const int*)d_in[1];
  const float* emb   = (const float*)d_in[2];
  const float* fus   = (const float*)d_in[3];
  const float* ret   = (const float*)d_in[4];
  const float* ln1g  = (const float*)d_in[5];
  const float* Wq    = (const float*)d_in[6];
  const float* Wkv   = (const float*)d_in[7];
  const float* Wo    = (const float*)d_in[8];
  const float* ln2g  = (const float*)d_in[9];
  const float* Wff1  = (const float*)d_in[10];
  const float* Wff2  = (const float*)d_in[11];
  const float* normg = (const float*)d_in[12];
  const float* pWkv  = (const float*)d_in[15];
  const float* pWo   = (const float*)d_in[16];
  const float* lsc   = (const float*)d_in[17];
  const float* lsf   = (const float*)d_in[18];

  char* ws = (char*)d_ws;
  float* t   = (float*)(ws + 0L);                // 4224*1024*4  = 17,301,504
  u16* xn    = (u16*)(ws + 17301504L);           // 4224*1024*2  =  8,650,752
  char* U    = ws + 25952256L;
  u16* qkv   = (u16*)(U);                        // 4352*3072*2  = 26,738,688
  u16* vtb   = (u16*)(U + 26738688L);            // 64*64*1040*2 + pad = 8,531,968
  u16* aout  = (u16*)(U + 35270656L);            // 4224*1024*2 (attn out; dead after Wo GEMM)
  u16* ab    = (u16*)(U + 35270656L);            // 4224*2752*2 = 23,248,896 (swiglu out; reuses aout slot)
  float* par0 = (float*)(U);                     // split-K partial 0: 4224*1024*4 = 17,301,504
  float* par1 = (float*)(U + 17301504L);         // split-K partial 1 (ends 34,603,008 < ab)
  char* WT   = ws + 95698944L;                   // per-layer weights (25,296,896), reused (L3-hot)
  u16* qkvT  = (u16*)(WT);                       // 3072*1024*2
  u16* WoT   = (u16*)(WT + 6291456L);            // 1024*1024*2
  u16* f1T   = (u16*)(WT + 8388608L);            // 5504*1024*2 (column-permuted swiglu layout)
  u16* f2T   = (u16*)(WT + 19660800L);           // 1024*2752*2
  char* FIN  = ws + 120995840L;
  float* rowm   = (float*)(FIN);
  float* rinvp  = (float*)(FIN + 16640L);
  float* colsum = (float*)(FIN + 33280L);
  float* msum   = (float*)(FIN + 49664L);
  float* tmp    = (float*)(FIN + 49728L);
  float* spl    = (float*)(FIN + 66112L);
  float* fub    = (float*)(FIN + 82496L);
  float* dots   = (float*)(FIN + 98880L);        // 36 floats
  const long PSTR = 4224L * 1024;

  embed_k<<<4160, 256, 0, stream>>>(sdata, sidx, emb, fus, t);

  for (int l = 0; l < 6; l++) {
    wtrans5_k<<<12352, 256, 0, stream>>>(
        Wq + (long)l * 1024 * 1024, Wkv + (long)l * 1024 * 2048,
        Wo + (long)l * 1024 * 1024, Wff1 + (long)l * 1024 * 5460,
        Wff2 + (long)l * 2730 * 1024, qkvT, WoT, f1T, f2T);

    // ln1 (layer 0: plain; else fused with previous layer's ff2 partial reduce)
    if (l == 0)
      ln_k<<<4160, 256, 0, stream>>>(t, ln1g, xn);
    else
      lnred_k<<<4160, 256, 0, stream>>>(t, par0, par1, ln1g + l * 1024, xn);

    // qkv GEMM (mode 2): writes qkv + fused V-transpose into vtb
    gemm_bt<<<33 * 24, 256, 0, stream>>>(xn, 1024, qkvT, 1024, qkv, 3072, 1024, 2, 33, 1, 0, vtb);
    attn_k<<<1088, 256, 0, stream>>>(qkv, vtb, aout);
    // Wo GEMM split-K=2 -> f32 partials at U (disjoint from aout/ab)
    gemm_bt<<<33 * 8 * 2, 256, 0, stream>>>(aout, 1024, WoT, 1024, par0, 1024, 1024, 1, 33, 2, PSTR, vtb);
    lnred_k<<<4160, 256, 0, stream>>>(t, par0, par1, ln2g + l * 1024, xn);
    // ff1 GEMM (mode 3): fused SwiGLU epilogue -> ab directly (no hb, no act_k)
    gemm_bt<<<33 * 43, 256, 0, stream>>>(xn, 1024, f1T, 1024, ab, 2752, 1024, 3, 33, 1, 0, vtb);
    // ff2 GEMM split-K=2 -> f32 partials at U (disjoint from ab)
    gemm_bt<<<33 * 8 * 2, 256, 0, stream>>>(ab, 2752, f2T, 2752, par0, 1024, 2752, 1, 33, 2, PSTR, vtb);
  }

  redrow_k<<<4160, 256, 0, stream>>>(t, par0, par1, rowm, rinvp);
  hipMemsetAsync(colsum, 0, 16448, stream);  // colsum + msum
  wcolsum_k<<<dim3(4, 52), 256, 0, stream>>>(t, rowm, rinvp, colsum, msum);
  mv1_k<<<dim3(4, 16), 256, 0, stream>>>(colsum, msum, normg, pWkv, tmp);
  mv2_k<<<dim3(4, 16), 256, 0, stream>>>(tmp, pWo, ret, spl, fub);
  dots_k<<<36, 256, 0, stream>>>(spl, fub, dots);
  loss_fin_k<<<1, 64, 0, stream>>>(dots, lsc, lsf, (float*)d_out);
}

// Round 18
// 1752.402 us; speedup vs baseline: 1.1028x; 1.0060x over previous
//
#include <hip/hip_runtime.h>

typedef unsigned short u16;
typedef unsigned long long u64;
typedef __attribute__((ext_vector_type(8))) short short8;
typedef __attribute__((ext_vector_type(4))) float f32x4;

__device__ __forceinline__ u16 f2b(float f) {
  union { float f; unsigned u; } x; x.f = f;
  unsigned r = x.u + 0x7fffu + ((x.u >> 16) & 1u);
  return (u16)(r >> 16);
}
__device__ __forceinline__ float b2f(u16 h) {
  union { unsigned u; float f; } x; x.u = ((unsigned)h) << 16;
  return x.f;
}
__device__ __forceinline__ void gld16(const void* g, void* l) {
  __builtin_amdgcn_global_load_lds(
      (__attribute__((address_space(1))) const void*)g,
      (__attribute__((address_space(3))) void*)l, 16, 0, 0);
}

// ---------------- embedding: t[b,n,:] = emb[idx]*data or fusion ----------------
__global__ __launch_bounds__(256) void embed_k(
    const float* __restrict__ data, const int* __restrict__ idx,
    const float* __restrict__ emb, const float* __restrict__ fus,
    float* __restrict__ t) {
  int row = blockIdx.x;            // 0..4159
  int b = row / 1040, n = row % 1040;
  int tid = threadIdx.x;
  const float4* src;
  float sc = 1.f;
  if (n < 1024) {
    int e = idx[b * 1024 + n];
    sc = data[b * 1024 + n];
    src = (const float4*)(emb + (long)e * 1024);
  } else {
    src = (const float4*)(fus + (long)(n - 1024) * 1024);
  }
  float4 v = src[tid];
  v.x *= sc; v.y *= sc; v.z *= sc; v.w *= sc;
  ((float4*)(t + (long)row * 1024))[tid] = v;
}

// ------------- fused 5-matrix weight transpose: f32 src[K][N] -> bf16 dst[Npad][Kpad]
//               f1T gets COLUMN-PERMUTED layout: new col nc (p=nc>>5,sub=nc&31):
//               sub<16 -> xh col p*16+sub ; sub>=16 -> gate col 2714+p*16+sub  -------------
__global__ __launch_bounds__(256) void wtrans5_k(
    const float* __restrict__ sWq, const float* __restrict__ sWkv,
    const float* __restrict__ sWo, const float* __restrict__ sW1,
    const float* __restrict__ sW2,
    u16* __restrict__ dQkvT, u16* __restrict__ dWoT,
    u16* __restrict__ dF1T, u16* __restrict__ dF2T) {
  int id = blockIdx.x;
  const float* src; u16* dst; int K, N, Kpad, nx; float sc = 1.f; int perm = 0;
  if (id < 1024)       { src = sWq;  dst = dQkvT;             K = 1024; N = 1024; Kpad = 1024; nx = 32; sc = 0.125f; }
  else if (id < 3072)  { id -= 1024; src = sWkv; dst = dQkvT + 1024 * 1024; K = 1024; N = 2048; Kpad = 1024; nx = 64; }
  else if (id < 4096)  { id -= 3072; src = sWo;  dst = dWoT;  K = 1024; N = 1024; Kpad = 1024; nx = 32; }
  else if (id < 9600)  { id -= 4096; src = sW1;  dst = dF1T;  K = 1024; N = 5504; Kpad = 1024; nx = 172; perm = 1; }
  else                 { id -= 9600; src = sW2;  dst = dF2T;  K = 2730; N = 1024; Kpad = 2752; nx = 32; }
  int n0 = (id % nx) * 32, k0 = (id / nx) * 32;
  __shared__ float tile[32][33];
  int x = threadIdx.x & 31, y = threadIdx.x >> 5;
#pragma unroll
  for (int i = 0; i < 4; i++) {
    int k = k0 + y + i * 8, n = n0 + x;
    float val = 0.f;
    if (perm) {
      int p = n >> 5, sub = n & 31;
      int o = (sub < 16) ? (p * 16 + sub) : (2714 + p * 16 + sub);
      bool ok = (sub < 16) ? (o < 2730) : (o < 5460);
      val = (k < K && ok) ? src[(long)k * 5460 + o] : 0.f;
    } else {
      val = (k < K && n < N) ? src[(long)k * N + n] * sc : 0.f;
    }
    tile[y + i * 8][x] = val;
  }
  __syncthreads();
#pragma unroll
  for (int i = 0; i < 4; i++) {
    int n = n0 + y + i * 8, k = k0 + x;
    dst[(long)n * Kpad + k] = f2b(tile[x][y + i * 8]);
  }
}

// ---------------- LayerNorm (biased var, eps 1e-5) -> bf16 ----------------
__global__ __launch_bounds__(256) void ln_k(
    const float* __restrict__ t, const float* __restrict__ g,
    u16* __restrict__ xn) {
  int row = blockIdx.x, tid = threadIdx.x;
  int wave = tid >> 6, lane = tid & 63;
  float4 v = ((const float4*)(t + (long)row * 1024))[tid];
  float s = v.x + v.y + v.z + v.w;
#pragma unroll
  for (int o = 32; o > 0; o >>= 1) s += __shfl_xor(s, o, 64);
  __shared__ float r1[4], r2[4];
  if (lane == 0) r1[wave] = s;
  __syncthreads();
  float mean = (r1[0] + r1[1] + r1[2] + r1[3]) * (1.f / 1024.f);
  float dx = v.x - mean, dy = v.y - mean, dz = v.z - mean, dw = v.w - mean;
  float q = dx * dx + dy * dy + dz * dz + dw * dw;
#pragma unroll
  for (int o = 32; o > 0; o >>= 1) q += __shfl_xor(q, o, 64);
  if (lane == 0) r2[wave] = q;
  __syncthreads();
  float var = (r2[0] + r2[1] + r2[2] + r2[3]) * (1.f / 1024.f);
  float inv = rsqrtf(var + 1e-5f);
  float4 gv = ((const float4*)g)[tid];
  u64 pack = (u64)f2b(dx * inv * gv.x)
           | ((u64)f2b(dy * inv * gv.y) << 16)
           | ((u64)f2b(dz * inv * gv.z) << 32)
           | ((u64)f2b(dw * inv * gv.w) << 48);
  *(u64*)(xn + (long)row * 1024 + tid * 4) = pack;
}

// ------- fused reduce(t += p0+p1) + LayerNorm -> bf16 -------
__global__ __launch_bounds__(256) void lnred_k(
    float* __restrict__ t, const float* __restrict__ p0, const float* __restrict__ p1,
    const float* __restrict__ g, u16* __restrict__ xn) {
  int row = blockIdx.x, tid = threadIdx.x;
  int wave = tid >> 6, lane = tid & 63;
  long base = (long)row * 1024;
  float4 v = ((const float4*)(t + base))[tid];
  float4 a = ((const float4*)(p0 + base))[tid];
  float4 bq = ((const float4*)(p1 + base))[tid];
  v.x += a.x + bq.x; v.y += a.y + bq.y; v.z += a.z + bq.z; v.w += a.w + bq.w;
  ((float4*)(t + base))[tid] = v;
  float s = v.x + v.y + v.z + v.w;
#pragma unroll
  for (int o = 32; o > 0; o >>= 1) s += __shfl_xor(s, o, 64);
  __shared__ float r1[4], r2[4];
  if (lane == 0) r1[wave] = s;
  __syncthreads();
  float mean = (r1[0] + r1[1] + r1[2] + r1[3]) * (1.f / 1024.f);
  float dx = v.x - mean, dy = v.y - mean, dz = v.z - mean, dw = v.w - mean;
  float q = dx * dx + dy * dy + dz * dz + dw * dw;
#pragma unroll
  for (int o = 32; o > 0; o >>= 1) q += __shfl_xor(q, o, 64);
  if (lane == 0) r2[wave] = q;
  __syncthreads();
  float var = (r2[0] + r2[1] + r2[2] + r2[3]) * (1.f / 1024.f);
  float inv = rsqrtf(var + 1e-5f);
  float4 gv = ((const float4*)g)[tid];
  u64 pack = (u64)f2b(dx * inv * gv.x)
           | ((u64)f2b(dy * inv * gv.y) << 16)
           | ((u64)f2b(dz * inv * gv.z) << 32)
           | ((u64)f2b(dw * inv * gv.w) << 48);
  *(u64*)(xn + base + tid * 4) = pack;
}

// ------- fused reduce(t += p0+p1) + final-LN row stats -------
__global__ __launch_bounds__(256) void redrow_k(
    float* __restrict__ t, const float* __restrict__ p0, const float* __restrict__ p1,
    float* __restrict__ rowm, float* __restrict__ rinv) {
  int row = blockIdx.x, tid = threadIdx.x;
  int wave = tid >> 6, lane = tid & 63;
  long base = (long)row * 1024;
  float4 v = ((const float4*)(t + base))[tid];
  float4 a = ((const float4*)(p0 + base))[tid];
  float4 bq = ((const float4*)(p1 + base))[tid];
  v.x += a.x + bq.x; v.y += a.y + bq.y; v.z += a.z + bq.z; v.w += a.w + bq.w;
  ((float4*)(t + base))[tid] = v;
  float s = v.x + v.y + v.z + v.w;
#pragma unroll
  for (int o = 32; o > 0; o >>= 1) s += __shfl_xor(s, o, 64);
  __shared__ float r1[4], r2[4];
  if (lane == 0) r1[wave] = s;
  __syncthreads();
  float mean = (r1[0] + r1[1] + r1[2] + r1[3]) * (1.f / 1024.f);
  float dx = v.x - mean, dy = v.y - mean, dz = v.z - mean, dw = v.w - mean;
  float q = dx * dx + dy * dy + dz * dz + dw * dw;
#pragma unroll
  for (int o = 32; o > 0; o >>= 1) q += __shfl_xor(q, o, 64);
  if (lane == 0) r2[wave] = q;
  __syncthreads();
  if (tid == 0) {
    float var = (r2[0] + r2[1] + r2[2] + r2[3]) * (1.f / 1024.f);
    rowm[row] = mean;
    rinv[row] = rsqrtf(var + 1e-5f);
  }
}

// ------- GEMM: C[M][N] = A[M][K](bf16) * Bt[N][K](bf16)^T, tile 128x128, BK=32
// 2-buffer counted-vmcnt pipeline (32KB LDS -> 5 blocks/CU): stage(t+2) issued into
// buf[t&1] AFTER the second barrier (race-free); iter-top vmcnt(4) ensures stage t landed.
// mode0: bf16 store; mode1: f32 store to partial ksp; mode2: bf16 + fused V-transpose;
// mode3: fused SwiGLU epilogue (permuted f1T; tanh-gelu; writes to C[ldc=2752])
// T2 XOR-swizzled LDS; bijective-XCD-swizzled 1D grid.
__global__ __launch_bounds__(256) void gemm_bt(
    const u16* __restrict__ A, int lda,
    const u16* __restrict__ Bt, int ldb,
    void* __restrict__ C, int ldc,
    int K, int mode, int gx, int ns, long pstride, u16* __restrict__ vt) {
  __shared__ u16 As[2][128 * 32];
  __shared__ u16 Bs[2][128 * 32];
  int tid = threadIdx.x;
  int wave = tid >> 6, lane = tid & 63;
  int col = lane & 15, grp = lane >> 4;
  // bijective XCD swizzle (m204)
  int nwg = gridDim.x;
  int id = blockIdx.x;
  int q = nwg >> 3, r = nwg & 7;
  int xcd = id & 7, off = id >> 3;
  int wgid = (xcd < r ? xcd * (q + 1) : r * (q + 1) + (xcd - r) * q) + off;
  int tiles = nwg / ns;
  int ksp = wgid / tiles;
  int rem = wgid % tiles;
  int bm = rem % gx, bn = rem / gx;
  int nst = K >> 5;
  int k0 = ((nst * ksp) / ns) << 5;
  int k1 = ((nst * (ksp + 1)) / ns) << 5;
  int sr = wave * 16 + (lane >> 2);
  // T2: pre-swizzled source k-chunk; LDS row r stores global chunk s^((r>>1)&3) at slot s.
  int sk = ((lane & 3) ^ ((lane >> 3) & 3)) * 8;
  const u16* aSrc = A + ((long)bm * 128 + sr) * lda + sk;
  const u16* bSrc = Bt + ((long)bn * 128 + sr) * ldb + sk;
  int wm = (wave >> 1) * 64, wn = (wave & 1) * 64;
  f32x4 acc[4][4] = {};

#define GSTAGE(buf, kt) do { \
    _Pragma("unroll") \
    for (int qq = 0; qq < 2; qq++) { \
      gld16(aSrc + (kt) + (long)qq * 64 * lda, &As[buf][wave * 512 + qq * 2048]); \
      gld16(bSrc + (kt) + (long)qq * 64 * ldb, &Bs[buf][wave * 512 + qq * 2048]); \
    } } while (0)

  // prologue: stage tiles 0 and 1 (4 vmem ops each)
  GSTAGE(0, k0);
  if (k0 + 32 < k1) GSTAGE(1, k0 + 32);
  int cur = 0;
  int slot = (grp ^ ((col >> 1) & 3)) * 8;     // swizzled read slot (u16)
  for (int kt = k0; kt < k1; kt += 32) {
    if (kt + 32 < k1) {
      asm volatile("s_waitcnt vmcnt(4)" ::: "memory");   // stage t landed; t+1 in flight
    } else {
      asm volatile("s_waitcnt vmcnt(0)" ::: "memory");   // last tile
    }
    __builtin_amdgcn_s_barrier();                        // stage t visible to all waves
    __builtin_amdgcn_sched_barrier(0);                   // no ds_read hoisting (rule #18)
    short8 af[4], bfv[4];
#pragma unroll
    for (int m = 0; m < 4; m++)
      af[m] = *(const short8*)&As[cur][(wm + m * 16 + col) * 32 + slot];
#pragma unroll
    for (int n = 0; n < 4; n++)
      bfv[n] = *(const short8*)&Bs[cur][(wn + n * 16 + col) * 32 + slot];
    __builtin_amdgcn_s_setprio(1);
#pragma unroll
    for (int m = 0; m < 4; m++)
#pragma unroll
      for (int n = 0; n < 4; n++)
        acc[m][n] = __builtin_amdgcn_mfma_f32_16x16x32_bf16(af[m], bfv[n], acc[m][n], 0, 0, 0);
    __builtin_amdgcn_s_setprio(0);
    __builtin_amdgcn_s_barrier();                        // all reads of buf[cur] done
    __builtin_amdgcn_sched_barrier(0);                   // no gld16 hoisting above barrier
    if (kt + 64 < k1) GSTAGE(cur, kt + 64);              // stage t+2 into freed buffer
    cur ^= 1;
  }
#undef GSTAGE
  long r0 = (long)bm * 128 + wm + grp * 4;
  int c0 = bn * 128 + wn + col;
  if (mode == 3) {
    // fused SwiGLU: fragment n even = xh block p, n odd = gate block p (same p)
    // tanh-form gelu (|err| < 3e-4 abs, far below bf16 rounding of the output)
    u16* Ab = (u16*)C;
#pragma unroll
    for (int m = 0; m < 4; m++)
#pragma unroll
      for (int np = 0; np < 2; np++) {
        int ac = ((bn * 4 + (wn >> 5) + np) << 4) + col;   // original pair index
#pragma unroll
        for (int rr = 0; rr < 4; rr++) {
          float xh = acc[m][np * 2][rr];
          float gt = acc[m][np * 2 + 1][rr];
          float rv = 0.f;
          if (ac < 2730) {
            float y = 1.5957691216f * (gt + 0.044715f * gt * gt * gt); // 2*sqrt(2/pi)*(...)
            float th = 1.f - 2.f / (__expf(y) + 1.f);
            rv = 0.5f * gt * (1.f + th) * xh;
          }
          Ab[(r0 + m * 16 + rr) * ldc + ac] = f2b(rv);
        }
      }
  } else if (mode != 1) {
    u16* Cb = (u16*)C;
#pragma unroll
    for (int m = 0; m < 4; m++)
#pragma unroll
      for (int n = 0; n < 4; n++)
#pragma unroll
        for (int rr = 0; rr < 4; rr++)
          Cb[(r0 + m * 16 + rr) * ldc + c0 + n * 16] = f2b(acc[m][n][rr]);
    if (mode == 2 && bn >= 16) {
      // fused V-transpose: vt[(b*16+h)*64 + d][j] = C[row=b*1040+j][2048 + h*64 + d]
#pragma unroll
      for (int m = 0; m < 4; m++) {
        long row = r0 + m * 16;                 // 4-aligned; 4 consecutive j in same b
        if (row < 4160) {
          int bidx = (int)(row / 1040);
          int j = (int)(row - (long)bidx * 1040);
#pragma unroll
          for (int n = 0; n < 4; n++) {
            int d = c0 + n * 16 - 2048;
            u64 pack = (u64)f2b(acc[m][n][0])
                     | ((u64)f2b(acc[m][n][1]) << 16)
                     | ((u64)f2b(acc[m][n][2]) << 32)
                     | ((u64)f2b(acc[m][n][3]) << 48);
            *(u64*)(vt + ((long)(bidx * 16 + (d >> 6)) * 64 + (d & 63)) * 1040 + j) = pack;
          }
        }
      }
    }
  } else {
    float* Cf = (float*)C + (long)ksp * pstride;
#pragma unroll
    for (int m = 0; m < 4; m++)
#pragma unroll
      for (int n = 0; n < 4; n++)
#pragma unroll
        for (int rr = 0; rr < 4; rr++)
          Cf[(r0 + m * 16 + rr) * ldc + c0 + n * 16] = acc[m][n][rr];
  }
}

// ------- fused flash attention: 64-row i-tiles, no-max softmax, ones-column MFMA row-sum,
//         swizzled LDS, T4 counted-vmcnt 2-buffer pipeline, XCD-chunked flat grid -------
__global__ __launch_bounds__(256) void attn_k(
    const u16* __restrict__ qkv, const u16* __restrict__ vt,
    u16* __restrict__ out) {
  int nwg = gridDim.x;
  int id = blockIdx.x;
  int q = nwg >> 3, r = nwg & 7;
  int xcd = id & 7, off = id >> 3;
  int wgid = (xcd < r ? xcd * (q + 1) : r * (q + 1) + (xcd - r) * q) + off;
  int bh = wgid / 17, it = wgid % 17;
  int b = bh >> 4, h = bh & 15;
  int tid = threadIdx.x, wave = tid >> 6, lane = tid & 63;
  int col = lane & 15, grp = lane >> 4;
  int i0 = it * 64;
  int jmax = (it == 16) ? 1040 : 1024;
  const u16* qb = qkv + (long)b * 1040 * 3072 + h * 64;
  const u16* kb = qkv + (long)b * 1040 * 3072 + 1024 + h * 64;
  const u16* vb = vt + (long)bh * 64 * 1040;
  __shared__ u16 Ks[2][64 * 64];
  __shared__ u16 Vs[2][64 * 64];
  __shared__ u16 Ps[4][16 * 64];

  int srow0 = wave * 8 + (lane >> 3);                 // row within 32-row half
  int gsw = ((lane & 7) ^ (srow0 & 7)) * 8;           // swizzled source col (u16)
#define ASTAGE(buf, j0s) do { \
    int jv = (j0s) + gsw; if (jv >= 1040) jv = 1032; \
    _Pragma("unroll") \
    for (int qq = 0; qq < 2; qq++) { \
      int rr = qq * 32 + srow0; \
      gld16(kb + (long)((j0s) + rr) * 3072 + gsw, &Ks[buf][qq * 2048 + wave * 512]); \
      gld16(vb + (long)rr * 1040 + jv, &Vs[buf][qq * 2048 + wave * 512]); \
    } } while (0)

  short8 aq[2];
  int qrow = i0 + wave * 16;
#pragma unroll
  for (int kf = 0; kf < 2; kf++)
    aq[kf] = *(const short8*)(qb + (long)(qrow + col) * 3072 + kf * 32 + grp * 8);

  short8 one8 = {};
  if (col == 0) {
#pragma unroll
    for (int i = 0; i < 8; i++) one8[i] = (short)0x3F80;   // bf16 1.0
  }

  f32x4 oa[4] = {};
  f32x4 oa1 = {};                                          // ones-column: row-sums in col 0

  ASTAGE(0, 0);           // 4 vmem ops
  int cur = 0;
  for (int j0 = 0; j0 < jmax; j0 += 64) {
    if (j0 + 64 < jmax) {
      ASTAGE(cur ^ 1, j0 + 64);                         // issue next tile (4 ops)
      asm volatile("s_waitcnt vmcnt(4)" ::: "memory");  // tile t landed; t+1 in flight
    } else {
      asm volatile("s_waitcnt vmcnt(0)" ::: "memory");  // last tile
    }
    __builtin_amdgcn_s_barrier();                       // tile t visible to all waves
    __builtin_amdgcn_sched_barrier(0);                  // no ds_read hoisting (rule #18)
    f32x4 s[4] = {};
#pragma unroll
    for (int kf = 0; kf < 2; kf++) {
      short8 bk[4];
#pragma unroll
      for (int n = 0; n < 4; n++) {
        int rk = n * 16 + col;
        bk[n] = *(const short8*)&Ks[cur][rk * 64 + ((kf * 32 + grp * 8) ^ ((rk & 7) << 3))];
      }
      __builtin_amdgcn_s_setprio(1);
#pragma unroll
      for (int n = 0; n < 4; n++)
        s[n] = __builtin_amdgcn_mfma_f32_16x16x32_bf16(aq[kf], bk[n], s[n], 0, 0, 0);
      __builtin_amdgcn_s_setprio(0);
    }
    if (j0 + 64 > jmax) {
      int lim = jmax - j0;
#pragma unroll
      for (int n = 0; n < 4; n++) {
        if (n * 16 + col >= lim) {
#pragma unroll
          for (int r2 = 0; r2 < 4; r2++) s[n][r2] = -1e30f;
        }
      }
    }
    // no-max softmax (scores structurally bounded); row-sum comes from ones-MFMA below
#pragma unroll
    for (int r2 = 0; r2 < 4; r2++) {
      int rp = grp * 4 + r2;
#pragma unroll
      for (int n = 0; n < 4; n++) {
        float p = __expf(s[n][r2]);
        Ps[wave][rp * 64 + ((n * 16 + col) ^ ((rp & 7) << 3))] = f2b(p);
      }
    }
#pragma unroll
    for (int kf = 0; kf < 2; kf++) {
      short8 ap, bv[4];
      int rm = col;
      ap = *(const short8*)&Ps[wave][rm * 64 + ((kf * 32 + grp * 8) ^ ((rm & 7) << 3))];
#pragma unroll
      for (int n = 0; n < 4; n++) {
        int rv = n * 16 + col;
        bv[n] = *(const short8*)&Vs[cur][rv * 64 + ((kf * 32 + grp * 8) ^ ((rv & 7) << 3))];
      }
      __builtin_amdgcn_s_setprio(1);
#pragma unroll
      for (int n = 0; n < 4; n++)
        oa[n] = __builtin_amdgcn_mfma_f32_16x16x32_bf16(ap, bv[n], oa[n], 0, 0, 0);
      oa1 = __builtin_amdgcn_mfma_f32_16x16x32_bf16(ap, one8, oa1, 0, 0, 0);
      __builtin_amdgcn_s_setprio(0);
    }
    __builtin_amdgcn_s_barrier();                       // all reads of buf[cur] done
    __builtin_amdgcn_sched_barrier(0);                  // no gld16 sinking above barrier
    cur ^= 1;
  }
#undef ASTAGE
  float lr[4];
#pragma unroll
  for (int r2 = 0; r2 < 4; r2++) lr[r2] = __shfl(oa1[r2], lane & 48, 64);  // broadcast col-0 row-sum
#pragma unroll
  for (int n = 0; n < 4; n++)
#pragma unroll
    for (int r2 = 0; r2 < 4; r2++) {
      int i = i0 + wave * 16 + grp * 4 + r2;
      if (i < 1040)
        out[((long)b * 1040 + i) * 1024 + h * 64 + n * 16 + col] = f2b(oa[n][r2] / lr[r2]);
    }
}

// ---------------- weighted column sum for token-mean pooling ----------------
__global__ __launch_bounds__(256) void wcolsum_k(
    const float* __restrict__ t, const float* __restrict__ rowm,
    const float* __restrict__ rinv, float* __restrict__ colsum,
    float* __restrict__ msum) {
  int b = blockIdx.x, c = blockIdx.y, tid = threadIdx.x;
  float a0 = 0, a1 = 0, a2 = 0, a3 = 0, ms = 0;
  for (int r = 0; r < 20; r++) {
    long row = (long)b * 1040 + c * 20 + r;
    float iv = rinv[row];
    float4 v = ((const float4*)(t + row * 1024))[tid];
    a0 += v.x * iv; a1 += v.y * iv; a2 += v.z * iv; a3 += v.w * iv;
    if (tid == 0) ms += rowm[row] * iv;
  }
  atomicAdd(&colsum[b * 1024 + tid * 4 + 0], a0);
  atomicAdd(&colsum[b * 1024 + tid * 4 + 1], a1);
  atomicAdd(&colsum[b * 1024 + tid * 4 + 2], a2);
  atomicAdd(&colsum[b * 1024 + tid * 4 + 3], a3);
  if (tid == 0) atomicAdd(&msum[b], ms);
}

// ------- pooled matvec 1 (parallel): tmp[b][n] = (1/1040) * sum_k mk[b][k]*pWkv[k][1024+n]
//         grid (4,16); 4 waves split K into 256-chunks; LDS reduce -------
__global__ __launch_bounds__(256) void mv1_k(
    const float* __restrict__ colsum, const float* __restrict__ msum,
    const float* __restrict__ g, const float* __restrict__ pWkv,
    float* __restrict__ tmp) {
  int b = blockIdx.x, n0 = blockIdx.y * 64;
  int tid = threadIdx.x;
  int n = tid & 63, s = tid >> 6;
  float msb = msum[b];
  float acc = 0.f;
  int ks = s * 256;
  for (int k = ks; k < ks + 256; k++) {
    float mk = g[k] * (colsum[b * 1024 + k] - msb);
    acc += mk * pWkv[(long)k * 2048 + 1024 + n0 + n];
  }
  __shared__ float red[4][64];
  red[s][n] = acc;
  __syncthreads();
  if (s == 0)
    tmp[b * 1024 + n0 + n] = (red[0][n] + red[1][n] + red[2][n] + red[3][n]) * (1.f / 1040.f);
}

// ------- pooled matvec 2 (parallel) + assemble spliced/fusion -------
__global__ __launch_bounds__(256) void mv2_k(
    const float* __restrict__ tmp, const float* __restrict__ pWo,
    const float* __restrict__ ret, float* __restrict__ spl,
    float* __restrict__ fub) {
  int b = blockIdx.x, n0 = blockIdx.y * 64;
  int tid = threadIdx.x;
  int n = tid & 63, s = tid >> 6;
  float acc = 0.f;
  int ks = s * 256;
  for (int k = ks; k < ks + 256; k++)
    acc += tmp[b * 1024 + k] * pWo[(long)k * 1024 + n0 + n];
  __shared__ float red[4][64];
  red[s][n] = acc;
  __syncthreads();
  if (s == 0) {
    float v = red[0][n] + red[1][n] + red[2][n] + red[3][n];
    spl[b * 1024 + n0 + n] = ret[n0 + n] + v;
    fub[b * 1024 + n0 + n] = ret[1024 + n0 + n] + v;
  }
}

// ---------------- contrastive loss: parallel dots (36 blocks) + tiny finisher ----------------
__global__ __launch_bounds__(256) void dots_k(
    const float* __restrict__ s, const float* __restrict__ f,
    float* __restrict__ dots) {
  int d = blockIdx.x, tid = threadIdx.x;
  int wave = tid >> 6, lane = tid & 63;
  const float *a, *bb;
  if (d < 16) { a = s + (d >> 2) * 1024; bb = s + (d & 3) * 1024; }
  else if (d < 32) { int e = d - 16; a = s + (e >> 2) * 1024; bb = f + (e & 3) * 1024; }
  else { a = f + (d - 32) * 1024; bb = a; }
  float4 va = ((const float4*)a)[tid];
  float4 vb = ((const float4*)bb)[tid];
  float p = va.x * vb.x + va.y * vb.y + va.z * vb.z + va.w * vb.w;
#pragma unroll
  for (int o = 32; o > 0; o >>= 1) p += __shfl_xor(p, o, 64);
  __shared__ float r[4];
  if (lane == 0) r[wave] = p;
  __syncthreads();
  if (tid == 0) dots[d] = r[0] + r[1] + r[2] + r[3];
}

__device__ float closs_dev(const float L[4][4]) {
  float la = 0.f, lb = 0.f;
  for (int i = 0; i < 4; i++) {
    float mx = fmaxf(fmaxf(L[i][0], L[i][1]), fmaxf(L[i][2], L[i][3]));
    float sm = expf(L[i][0] - mx) + expf(L[i][1] - mx) + expf(L[i][2] - mx) + expf(L[i][3] - mx);
    la += mx + logf(sm) - L[i][i];
  }
  for (int j = 0; j < 4; j++) {
    float mx = fmaxf(fmaxf(L[0][j], L[1][j]), fmaxf(L[2][j], L[3][j]));
    float sm = expf(L[0][j] - mx) + expf(L[1][j] - mx) + expf(L[2][j] - mx) + expf(L[3][j] - mx);
    lb += mx + logf(sm) - L[j][j];
  }
  return 0.125f * (la + lb);  // ((la/4)+(lb/4))*0.5
}

__global__ __launch_bounds__(64) void loss_fin_k(
    const float* __restrict__ dots,
    const float* __restrict__ lsc, const float* __restrict__ lsf,
    float* __restrict__ out) {
  if (threadIdx.x == 0) {
    float nS[4], nF[4];
    for (int i = 0; i < 4; i++) { nS[i] = sqrtf(dots[i * 4 + i]); nF[i] = sqrtf(dots[32 + i]); }
    float e1 = expf(lsc[0]), e2 = expf(lsf[0]);
    float L1[4][4], L2[4][4];
    for (int i = 0; i < 4; i++)
      for (int j = 0; j < 4; j++) {
        L1[i][j] = e1 * dots[i * 4 + j] / (nS[i] * nS[j]);
        L2[i][j] = e2 * dots[16 + i * 4 + j] / (nS[i] * nF[j]);
      }
    out[0] = closs_dev(L1) + closs_dev(L2);
  }
}

extern "C" void kernel_launch(void* const* d_in, const int* in_sizes, int n_in,
                              void* d_out, int out_size, void* d_ws, size_t ws_size,
                              hipStream_t stream) {
  (void)in_sizes; (void)n_in; (void)out_size; (void)ws_size;
  const float* sdata = (const float*)d_in[0];
  const int*   sidx  = (const int*)d_in[1];
  const float* emb   = (const float*)d_in[2];
  const float* fus   = (const float*)d_in[3];
  const float* ret   = (const float*)d_in[4];
  const float* ln1g  = (const float*)d_in[5];
  const float* Wq    = (const float*)d_in[6];
  const float* Wkv   = (const float*)d_in[7];
  const float* Wo    = (const float*)d_in[8];
  const float* ln2g  = (const float*)d_in[9];
  const float* Wff1  = (const float*)d_in[10];
  const float* Wff2  = (const float*)d_in[11];
  const float* normg = (const float*)d_in[12];
  const float* pWkv  = (const float*)d_in[15];
  const float* pWo   = (const float*)d_in[16];
  const float* lsc   = (const float*)d_in[17];
  const float* lsf   = (const float*)d_in[18];

  char* ws = (char*)d_ws;
  float* t   = (float*)(ws + 0L);                // 4224*1024*4  = 17,301,504
  u16* xn    = (u16*)(ws + 17301504L);           // 4224*1024*2  =  8,650,752
  char* U    = ws + 25952256L;
  u16* qkv   = (u16*)(U);                        // 4352*3072*2  = 26,738,688
  u16* vtb   = (u16*)(U + 26738688L);            // 64*64*1040*2 + pad = 8,531,968
  u16* aout  = (u16*)(U + 35270656L);            // 4224*1024*2 (attn out; dead after Wo GEMM)
  u16* ab    = (u16*)(U + 35270656L);            // 4224*2752*2 = 23,248,896 (swiglu out; reuses aout slot)
  float* par0 = (float*)(U);                     // split-K partial 0: 4224*1024*4 = 17,301,504
  float* par1 = (float*)(U + 17301504L);         // split-K partial 1 (ends 34,603,008 < ab)
  char* WT   = ws + 95698944L;                   // per-layer weights (25,296,896), reused (L3-hot)
  u16* qkvT  = (u16*)(WT);                       // 3072*1024*2
  u16* WoT   = (u16*)(WT + 6291456L);            // 1024*1024*2
  u16* f1T   = (u16*)(WT + 8388608L);            // 5504*1024*2 (column-permuted swiglu layout)
  u16* f2T   = (u16*)(WT + 19660800L);           // 1024*2752*2
  char* FIN  = ws + 120995840L;
  float* rowm   = (float*)(FIN);
  float* rinvp  = (float*)(FIN + 16640L);
  float* colsum = (float*)(FIN + 33280L);
  float* msum   = (float*)(FIN + 49664L);
  float* tmp    = (float*)(FIN + 49728L);
  float* spl    = (float*)(FIN + 66112L);
  float* fub    = (float*)(FIN + 82496L);
  float* dots   = (float*)(FIN + 98880L);        // 36 floats
  const long PSTR = 4224L * 1024;

  embed_k<<<4160, 256, 0, stream>>>(sdata, sidx, emb, fus, t);

  for (int l = 0; l < 6; l++) {
    wtrans5_k<<<12352, 256, 0, stream>>>(
        Wq + (long)l * 1024 * 1024, Wkv + (long)l * 1024 * 2048,
        Wo + (long)l * 1024 * 1024, Wff1 + (long)l * 1024 * 5460,
        Wff2 + (long)l * 2730 * 1024, qkvT, WoT, f1T, f2T);

    // ln1 (layer 0: plain; else fused with previous layer's ff2 partial reduce)
    if (l == 0)
      ln_k<<<4160, 256, 0, stream>>>(t, ln1g, xn);
    else
      lnred_k<<<4160, 256, 0, stream>>>(t, par0, par1, ln1g + l * 1024, xn);

    // qkv GEMM (mode 2): writes qkv + fused V-transpose into vtb
    gemm_bt<<<33 * 24, 256, 0, stream>>>(xn, 1024, qkvT, 1024, qkv, 3072, 1024, 2, 33, 1, 0, vtb);
    attn_k<<<1088, 256, 0, stream>>>(qkv, vtb, aout);
    // Wo GEMM split-K=2 -> f32 partials at U (disjoint from aout/ab)
    gemm_bt<<<33 * 8 * 2, 256, 0, stream>>>(aout, 1024, WoT, 1024, par0, 1024, 1024, 1, 33, 2, PSTR, vtb);
    lnred_k<<<4160, 256, 0, stream>>>(t, par0, par1, ln2g + l * 1024, xn);
    // ff1 GEMM (mode 3): fused SwiGLU epilogue -> ab directly (no hb, no act_k)
    gemm_bt<<<33 * 43, 256, 0, stream>>>(xn, 1024, f1T, 1024, ab, 2752, 1024, 3, 33, 1, 0, vtb);
    // ff2 GEMM split-K=2 -> f32 partials at U (disjoint from ab)
    gemm_bt<<<33 * 8 * 2, 256, 0, stream>>>(ab, 2752, f2T, 2752, par0, 1024, 2752, 1, 33, 2, PSTR, vtb);
  }

  redrow_k<<<4160, 256, 0, stream>>>(t, par0, par1, rowm, rinvp);
  hipMemsetAsync(colsum, 0, 16448, stream);  // colsum + msum
  wcolsum_k<<<dim3(4, 52), 256, 0, stream>>>(t, rowm, rinvp, colsum, msum);
  mv1_k<<<dim3(4, 16), 256, 0, stream>>>(colsum, msum, normg, pWkv, tmp);
  mv2_k<<<dim3(4, 16), 256, 0, stream>>>(tmp, pWo, ret, spl, fub);
  dots_k<<<36, 256, 0, stream>>>(spl, fub, dots);
  loss_fin_k<<<1, 64, 0, stream>>>(dots, lsc, lsf, (float*)d_out);
}